// Round 2
// baseline (6635.408 us; speedup 1.0000x reference)
//
#include <hip/hip_runtime.h>
#include <hip/hip_cooperative_groups.h>

namespace cg = cooperative_groups;

using u16 = unsigned short;
using u32 = unsigned int;

typedef __bf16 bf16x8 __attribute__((ext_vector_type(8)));
typedef float  f32x4  __attribute__((ext_vector_type(4)));
typedef u16    u16x8  __attribute__((ext_vector_type(8)));

static constexpr int kV = 32000, kH = 1024, kB = 64, kT = 64, kL = 4, kEOS = 2;

__device__ __forceinline__ u16 f2bf(float f) {
  u32 u = __float_as_uint(f);
  u = (u + 0x7fffu + ((u >> 16) & 1u)) >> 16;
  return (u16)u;
}
__device__ __forceinline__ float sigf(float x)   { return 1.0f / (1.0f + __expf(-x)); }
__device__ __forceinline__ float tanhf_(float x) { return 1.0f - 2.0f / (__expf(2.0f * x) + 1.0f); }

typedef const __attribute__((address_space(1))) u32* gas_ptr;
typedef __attribute__((address_space(3))) u32*       las_ptr;
__device__ __forceinline__ void async16(const u16* g, u16* l) {
  // LDS dest is wave-uniform base; HW writes base + lane*16B. Global src is per-lane.
  __builtin_amdgcn_global_load_lds((gas_ptr)g, (las_ptr)l, 16, 0, 0);
}

// ---------------- prep kernels ----------------

// Pack LSTM weights to per-block MFMA-fragment order (bf16):
// wpack[blk(256)][mat(2)][kk(32)][cf(4)][lane(64)][8]
__global__ void pack_lstm(const float* __restrict__ Wih, const float* __restrict__ Whh,
                          u16* __restrict__ wpack) {
  const int cid  = blockIdx.x * 256 + threadIdx.x;   // < 4,194,304
  const int lane = cid & 63;
  const int cf   = (cid >> 6) & 3;
  const int kk   = (cid >> 8) & 31;
  const int mt   = (cid >> 13) & 1;
  const int blk  = cid >> 14;
  const int lay = blk >> 6, cb = blk & 63;
  const int wr = cf * 1024 + cb * 16 + (lane & 15);
  const int kb = kk * 32 + (lane >> 4) * 8;
  const float* src = (mt ? Whh : Wih) + ((size_t)lay * 4096 + wr) * 1024 + kb;
  const float4* s4 = (const float4*)src;
  float4 v0 = s4[0], v1 = s4[1];
  u16x8 r;
  r[0]=f2bf(v0.x); r[1]=f2bf(v0.y); r[2]=f2bf(v0.z); r[3]=f2bf(v0.w);
  r[4]=f2bf(v1.x); r[5]=f2bf(v1.y); r[6]=f2bf(v1.z); r[7]=f2bf(v1.w);
  *(u16x8*)(wpack + (size_t)cid * 8) = r;
}

__global__ void pack_cls(const float* __restrict__ W, u16* __restrict__ o) {
  const size_t cid = (size_t)blockIdx.x * 256 + threadIdx.x;  // < 4,096,000
  const float4* s4 = (const float4*)(W + cid * 8);
  float4 v0 = s4[0], v1 = s4[1];
  u16x8 r;
  r[0]=f2bf(v0.x); r[1]=f2bf(v0.y); r[2]=f2bf(v0.z); r[3]=f2bf(v0.w);
  r[4]=f2bf(v1.x); r[5]=f2bf(v1.y); r[6]=f2bf(v1.z); r[7]=f2bf(v1.w);
  *(u16x8*)(o + cid * 8) = r;
}

// X[t][b][k] = bf16(embedding[t==0 ? EOS : tgt[b][t-1]][k])
__global__ void pack_x(const float* __restrict__ emb, const int* __restrict__ tgt,
                       u16* __restrict__ X) {
  const int cid = blockIdx.x * 256 + threadIdx.x;    // < 524,288
  const int kc = cid & 127, b = (cid >> 7) & 63, t = cid >> 13;
  const int tok = (t == 0) ? kEOS : tgt[b * 64 + t - 1];
  const float4* s4 = (const float4*)(emb + (size_t)tok * 1024 + kc * 8);
  float4 v0 = s4[0], v1 = s4[1];
  u16x8 r;
  r[0]=f2bf(v0.x); r[1]=f2bf(v0.y); r[2]=f2bf(v0.z); r[3]=f2bf(v0.w);
  r[4]=f2bf(v1.x); r[5]=f2bf(v1.y); r[6]=f2bf(v1.z); r[7]=f2bf(v1.w);
  *(u16x8*)(X + (size_t)cid * 8) = r;
}

// FIXED: h0 has L*B*H = 262,144 floats = 32,768 vec8 (was 65,536 -> OOB read+write)
__global__ void pack_init(const float* __restrict__ h0, const float* __restrict__ bih,
                          const float* __restrict__ bhh, u16* __restrict__ hbinit,
                          float* __restrict__ bsum) {
  const int cid = blockIdx.x * 256 + threadIdx.x;    // grid = 192*256 = 49,152 exact
  if (cid < 32768) {
    const float4* s4 = (const float4*)(h0 + (size_t)cid * 8);
    float4 v0 = s4[0], v1 = s4[1];
    u16x8 r;
    r[0]=f2bf(v0.x); r[1]=f2bf(v0.y); r[2]=f2bf(v0.z); r[3]=f2bf(v0.w);
    r[4]=f2bf(v1.x); r[5]=f2bf(v1.y); r[6]=f2bf(v1.z); r[7]=f2bf(v1.w);
    *(u16x8*)(hbinit + (size_t)cid * 8) = r;
  } else {
    const int i = cid - 32768;   // < 16384 = L*4H
    bsum[i] = bih[i] + bhh[i];
  }
}

// ---------------- cooperative wavefront recurrence ----------------
// grid 256 blocks x 512 thr. block: layer = blk>>6, 16 hidden units (64 gate cols).
// 8 waves: mat = wave>>2 (0: x@Wi^T, 1: h@Wh^T), wm=(wave>>1)&1, wc=wave&1 (32x32 subtiles).
__global__ void __launch_bounds__(512)
lstm_coop(const u16* __restrict__ wpack, const u16* __restrict__ xall,
          u16* __restrict__ h3all, u16* __restrict__ hb,
          const u16* __restrict__ hbinit, const float* __restrict__ bsum,
          const float* __restrict__ c0, float* __restrict__ outh, float* __restrict__ outc) {
  __shared__ u16 stg[3][8192];   // slot: A-x[4][64][8] | A-h[4][64][8] | B-Wi[4][64][8] | B-Wh[4][64][8]
  __shared__ float G[4096];      // 64 rows(batch) x 64 cols(gate*16+unit)

  const int tid  = threadIdx.x;
  const int lane = tid & 63;
  const int wave = tid >> 6;
  const int mat  = wave >> 2;
  const int wm   = (wave >> 1) & 1;
  const int wc   = wave & 1;
  const int l15  = lane & 15;
  const int l4   = lane >> 4;

  const int blk = blockIdx.x;
  const int lay = blk >> 6;
  const int cb  = blk & 63;
  const int u0  = cb << 4;

  const int ub = tid >> 3;          // batch owned for cell update
  const int uu = (tid & 7) * 2;     // 2 units per thread

  float creg0 = c0[((size_t)lay * 64 + ub) * 1024 + u0 + uu];
  float creg1 = c0[((size_t)lay * 64 + ub) * 1024 + u0 + uu + 1];

  float bsv[8];
  #pragma unroll
  for (int g = 0; g < 4; ++g) {
    bsv[g]     = bsum[lay * 4096 + g * 1024 + u0 + uu];
    bsv[4 + g] = bsum[lay * 4096 + g * 1024 + u0 + uu + 1];
  }

  const size_t wbase = (size_t)blk * 131072;
  cg::grid_group grid = cg::this_grid();

  for (int s = 0; s < kT + kL - 1; ++s) {
    const int t = s - lay;
    if (t >= 0 && t < kT) {
      const u16* xsrc = (lay == 0) ? (xall + (size_t)t * 65536)
                                   : (hb + ((size_t)(lay - 1) * 2 + (t & 1)) * 65536);
      const u16* hsrc = (t == 0) ? (hbinit + (size_t)lay * 65536)
                      : ((lay == 3) ? (h3all + (size_t)(t - 1) * 65536)
                                    : (hb + ((size_t)lay * 2 + ((t - 1) & 1)) * 65536));

      f32x4 acc00 = {0,0,0,0}, acc01 = {0,0,0,0}, acc10 = {0,0,0,0}, acc11 = {0,0,0,0};

      auto STAGE = [&](int c) {
        u16* slot = stg[c % 3];
        #pragma unroll
        for (int q = 0; q < 2; ++q) {
          const int u = wave * 2 + q;
          if (u < 8) {                      // activations: [mat][khi][row(=lane)][8]
            const int m2 = u >> 2, khi = u & 3;
            const u16* g = (m2 ? hsrc : xsrc) + (size_t)lane * 1024 + c * 32 + khi * 8;
            async16(g, slot + m2 * 2048 + khi * 512);
          } else {                          // weights: frag-packed, contiguous
            const int v = u - 8, m2 = v >> 2, cf = v & 3;
            const u16* g = wpack + wbase + ((size_t)(m2 * 32 + c) * 4 + cf) * 512 + lane * 8;
            async16(g, slot + 4096 + m2 * 2048 + cf * 512);
          }
        }
      };

      STAGE(0); STAGE(1);
      for (int c = 0; c < 32; ++c) {
        if (c < 30) STAGE(c + 2);
        if (c < 30)       asm volatile("s_waitcnt vmcnt(4)" ::: "memory");
        else if (c == 30) asm volatile("s_waitcnt vmcnt(2)" ::: "memory");
        else              asm volatile("s_waitcnt vmcnt(0)" ::: "memory");
        __builtin_amdgcn_s_barrier();
        asm volatile("" ::: "memory");
        const u16* sl = stg[c % 3];
        const u16* As = sl + mat * 2048;
        const u16* Bs = sl + 4096 + mat * 2048;
        bf16x8 a0 = *(const bf16x8*)(As + l4 * 512 + (wm * 32 + 0  + l15) * 8);
        bf16x8 a1 = *(const bf16x8*)(As + l4 * 512 + (wm * 32 + 16 + l15) * 8);
        bf16x8 b0 = *(const bf16x8*)(Bs + (wc * 2 + 0) * 512 + lane * 8);
        bf16x8 b1 = *(const bf16x8*)(Bs + (wc * 2 + 1) * 512 + lane * 8);
        acc00 = __builtin_amdgcn_mfma_f32_16x16x32_bf16(a0, b0, acc00, 0, 0, 0);
        acc01 = __builtin_amdgcn_mfma_f32_16x16x32_bf16(a0, b1, acc01, 0, 0, 0);
        acc10 = __builtin_amdgcn_mfma_f32_16x16x32_bf16(a1, b0, acc10, 0, 0, 0);
        acc11 = __builtin_amdgcn_mfma_f32_16x16x32_bf16(a1, b1, acc11, 0, 0, 0);
        asm volatile("" ::: "memory");
        __builtin_amdgcn_s_barrier();
      }

      // G assembly: mat0 waves write, mat1 waves add
      if (mat == 0) {
        #pragma unroll
        for (int mi = 0; mi < 2; ++mi)
          #pragma unroll
          for (int ci = 0; ci < 2; ++ci) {
            const f32x4 a = (mi == 0 ? (ci == 0 ? acc00 : acc01) : (ci == 0 ? acc10 : acc11));
            #pragma unroll
            for (int r = 0; r < 4; ++r)
              G[(wm * 32 + mi * 16 + l4 * 4 + r) * 64 + wc * 32 + ci * 16 + l15] = a[r];
          }
      }
      __syncthreads();
      if (mat == 1) {
        #pragma unroll
        for (int mi = 0; mi < 2; ++mi)
          #pragma unroll
          for (int ci = 0; ci < 2; ++ci) {
            const f32x4 a = (mi == 0 ? (ci == 0 ? acc00 : acc01) : (ci == 0 ? acc10 : acc11));
            #pragma unroll
            for (int r = 0; r < 4; ++r)
              G[(wm * 32 + mi * 16 + l4 * 4 + r) * 64 + wc * 32 + ci * 16 + l15] += a[r];
          }
      }
      __syncthreads();

      // cell update (each thread: 1 batch row, 2 units; c-state lives in VGPRs)
      #pragma unroll
      for (int p = 0; p < 2; ++p) {
        const int u = uu + p;
        const float gi = G[ub * 64 +      u] + bsv[p * 4 + 0];
        const float gf = G[ub * 64 + 16 + u] + bsv[p * 4 + 1];
        const float gg = G[ub * 64 + 32 + u] + bsv[p * 4 + 2];
        const float go = G[ub * 64 + 48 + u] + bsv[p * 4 + 3];
        const float cr = (p == 0) ? creg0 : creg1;
        const float c2 = sigf(gf) * cr + sigf(gi) * tanhf_(gg);
        const float h2 = sigf(go) * tanhf_(c2);
        if (p == 0) creg0 = c2; else creg1 = c2;
        const u16 hv = f2bf(h2);
        if (lay == 3) h3all[(size_t)t * 65536 + ub * 1024 + u0 + u] = hv;
        else          hb[((size_t)lay * 2 + (t & 1)) * 65536 + ub * 1024 + u0 + u] = hv;
        if (t == kT - 1) {
          outh[((size_t)lay * 64 + ub) * 1024 + u0 + u] = h2;
          outc[((size_t)lay * 64 + ub) * 1024 + u0 + u] = c2;
        }
      }
      __threadfence();   // drains stores (vmcnt(0)) + device-scope release
    }
    grid.sync();
  }
}

// ---------------- classifier GEMM (full path): A(4096x1024 bf16) @ Bw^T, Bw pre-packed bf16 ----------------
__global__ void __launch_bounds__(256)
cls_gemm(const u16* __restrict__ A, const u16* __restrict__ Bw,
         const float* __restrict__ bcls, float* __restrict__ out) {
  __shared__ u16 sA[2][4096], sB[2][4096];   // [khi4][row128][8]
  const int tid = threadIdx.x, lane = tid & 63, wave = tid >> 6;
  const int wm = wave >> 1, wc = wave & 1;
  const int l15 = lane & 15, l4 = lane >> 4;
  const int bn = blockIdx.x, bm = blockIdx.y;
  const u16* Ab = A  + (size_t)bm * 131072;
  const u16* Bb = Bw + (size_t)bn * 131072;

  auto STAGE = [&](int kk) {
    u16* dA = sA[kk & 1]; u16* dB = sB[kk & 1];
    #pragma unroll
    for (int q = 0; q < 4; ++q) {
      const int u = wave * 4 + q, v = u & 7;
      const u16* g = ((u < 8) ? Ab : Bb) + (size_t)((v & 1) * 64 + lane) * 1024 + kk * 32 + (v >> 1) * 8;
      async16(g, ((u < 8) ? dA : dB) + v * 512);
    }
  };

  f32x4 acc[4][4] = {};
  STAGE(0);
  for (int kk = 0; kk < 32; ++kk) {
    if (kk < 31) { STAGE(kk + 1); asm volatile("s_waitcnt vmcnt(4)" ::: "memory"); }
    else         asm volatile("s_waitcnt vmcnt(0)" ::: "memory");
    __builtin_amdgcn_s_barrier();
    asm volatile("" ::: "memory");
    const u16* aS = sA[kk & 1]; const u16* bS = sB[kk & 1];
    bf16x8 av[4], bv[4];
    #pragma unroll
    for (int mi = 0; mi < 4; ++mi) av[mi] = *(const bf16x8*)(aS + l4 * 1024 + (wm * 64 + mi * 16 + l15) * 8);
    #pragma unroll
    for (int ci = 0; ci < 4; ++ci) bv[ci] = *(const bf16x8*)(bS + l4 * 1024 + (wc * 64 + ci * 16 + l15) * 8);
    #pragma unroll
    for (int mi = 0; mi < 4; ++mi)
      #pragma unroll
      for (int ci = 0; ci < 4; ++ci)
        acc[mi][ci] = __builtin_amdgcn_mfma_f32_16x16x32_bf16(av[mi], bv[ci], acc[mi][ci], 0, 0, 0);
    asm volatile("" ::: "memory");
    __builtin_amdgcn_s_barrier();
  }
  #pragma unroll
  for (int ci = 0; ci < 4; ++ci) {
    const int col = bn * 128 + wc * 64 + ci * 16 + l15;
    const float bc = bcls[col];
    #pragma unroll
    for (int mi = 0; mi < 4; ++mi) {
      #pragma unroll
      for (int r = 0; r < 4; ++r) {
        const int row = bm * 128 + wm * 64 + mi * 16 + l4 * 4 + r;
        out[(size_t)row * 32000 + col] = acc[mi][ci][r] + bc;
      }
    }
  }
}

// ---------------- classifier GEMM (compact path): Bw is f32, converted on the fly ----------------
__global__ void __launch_bounds__(256)
cls_gemm_f32(const u16* __restrict__ A, const float* __restrict__ Bw,
             const float* __restrict__ bcls, float* __restrict__ out) {
  __shared__ u16 sA[2][4096], sB[2][4096];
  const int tid = threadIdx.x, lane = tid & 63, wave = tid >> 6;
  const int wm = wave >> 1, wc = wave & 1;
  const int l15 = lane & 15, l4 = lane >> 4;
  const int bn = blockIdx.x, bm = blockIdx.y;
  const u16*  Ab = A  + (size_t)bm * 131072;
  const float* Bb = Bw + (size_t)bm * 0 + (size_t)bn * 131072;  // 128 rows x 1024 f32

  // thread owns B positions p = tid and tid+256 of 512 (p = khi*128 + row)
  auto LOADB = [&](int kk, u16x8* rb) {
    #pragma unroll
    for (int q = 0; q < 2; ++q) {
      const int p = tid + q * 256, row = p & 127, khi = p >> 7;
      const float4* s4 = (const float4*)(Bb + (size_t)row * 1024 + kk * 32 + khi * 8);
      float4 v0 = s4[0], v1 = s4[1];
      u16x8 r;
      r[0]=f2bf(v0.x); r[1]=f2bf(v0.y); r[2]=f2bf(v0.z); r[3]=f2bf(v0.w);
      r[4]=f2bf(v1.x); r[5]=f2bf(v1.y); r[6]=f2bf(v1.z); r[7]=f2bf(v1.w);
      rb[q] = r;
    }
  };
  auto WRITEB = [&](int kk, const u16x8* rb) {
    u16* dB = sB[kk & 1];
    #pragma unroll
    for (int q = 0; q < 2; ++q) {
      const int p = tid + q * 256;
      *(u16x8*)(dB + p * 8) = rb[q];
    }
  };
  auto STAGE_A = [&](int kk) {   // 4 waves x 2 segments, after B-loads (in-order vmcnt retirement)
    u16* dA = sA[kk & 1];
    #pragma unroll
    for (int q = 0; q < 2; ++q) {
      const int v = wave * 2 + q;
      const u16* g = Ab + (size_t)((v & 1) * 64 + lane) * 1024 + kk * 32 + (v >> 1) * 8;
      async16(g, dA + v * 512);
    }
  };

  f32x4 acc[4][4] = {};
  {
    u16x8 rb[2];
    LOADB(0, rb); STAGE_A(0); WRITEB(0, rb);
  }
  for (int kk = 0; kk < 32; ++kk) {
    if (kk < 31) {
      u16x8 rb[2];
      LOADB(kk + 1, rb);      // f32 loads issued first
      STAGE_A(kk + 1);        // async16 after -> draining B-loads also drains A(kk)
      WRITEB(kk + 1, rb);     // compiler waits the f32 loads here (in-order => A(kk) done too)
    } else {
      asm volatile("s_waitcnt vmcnt(0)" ::: "memory");
    }
    __builtin_amdgcn_s_barrier();
    asm volatile("" ::: "memory");
    const u16* aS = sA[kk & 1]; const u16* bS = sB[kk & 1];
    bf16x8 av[4], bv[4];
    #pragma unroll
    for (int mi = 0; mi < 4; ++mi) av[mi] = *(const bf16x8*)(aS + l4 * 1024 + (wm * 64 + mi * 16 + l15) * 8);
    #pragma unroll
    for (int ci = 0; ci < 4; ++ci) bv[ci] = *(const bf16x8*)(bS + l4 * 1024 + (wc * 64 + ci * 16 + l15) * 8);
    #pragma unroll
    for (int mi = 0; mi < 4; ++mi)
      #pragma unroll
      for (int ci = 0; ci < 4; ++ci)
        acc[mi][ci] = __builtin_amdgcn_mfma_f32_16x16x32_bf16(av[mi], bv[ci], acc[mi][ci], 0, 0, 0);
    asm volatile("" ::: "memory");
    __builtin_amdgcn_s_barrier();
  }
  #pragma unroll
  for (int ci = 0; ci < 4; ++ci) {
    const int col = bn * 128 + wc * 64 + ci * 16 + l15;
    const float bc = bcls[col];
    #pragma unroll
    for (int mi = 0; mi < 4; ++mi) {
      #pragma unroll
      for (int r = 0; r < 4; ++r) {
        const int row = bm * 128 + wm * 64 + mi * 16 + l4 * 4 + r;
        out[(size_t)row * 32000 + col] = acc[mi][ci][r] + bc;
      }
    }
  }
}

// ---------------- log-softmax ----------------
__global__ void __launch_bounds__(256)
logz_k(const float* __restrict__ out, float* __restrict__ logz) {
  __shared__ float red[256];
  const int r = blockIdx.x;
  const float* p = out + (size_t)r * 32000;
  float m = -3.0e38f;
  for (int v = threadIdx.x; v < 32000; v += 256) m = fmaxf(m, p[v]);
  red[threadIdx.x] = m; __syncthreads();
  for (int s2 = 128; s2 > 0; s2 >>= 1) {
    if ((int)threadIdx.x < s2) red[threadIdx.x] = fmaxf(red[threadIdx.x], red[threadIdx.x + s2]);
    __syncthreads();
  }
  m = red[0]; __syncthreads();
  float s = 0.0f;
  for (int v = threadIdx.x; v < 32000; v += 256) s += __expf(p[v] - m);
  red[threadIdx.x] = s; __syncthreads();
  for (int s2 = 128; s2 > 0; s2 >>= 1) {
    if ((int)threadIdx.x < s2) red[threadIdx.x] += red[threadIdx.x + s2];
    __syncthreads();
  }
  if (threadIdx.x == 0) logz[r] = m + logf(red[0]);
}

__global__ void __launch_bounds__(256)
sub_k(float* __restrict__ out, const float* __restrict__ logz) {
  const int r = blockIdx.x;
  const float z = logz[r];
  float* p = out + (size_t)r * 32000;
  for (int v = threadIdx.x; v < 32000; v += 256) p[v] -= z;
}

// ---------------- host ----------------
extern "C" void kernel_launch(void* const* d_in, const int* in_sizes, int n_in,
                              void* d_out, int out_size, void* d_ws, size_t ws_size,
                              hipStream_t stream) {
  (void)in_sizes; (void)n_in; (void)out_size;
  const int*   tgt  = (const int*)d_in[1];
  const float* h0   = (const float*)d_in[2];
  const float* c0   = (const float*)d_in[3];
  const float* emb  = (const float*)d_in[4];
  const float* Wih  = (const float*)d_in[5];
  const float* Whh  = (const float*)d_in[6];
  const float* bih  = (const float*)d_in[7];
  const float* bhh  = (const float*)d_in[8];
  const float* Wcls = (const float*)d_in[9];
  const float* bcls = (const float*)d_in[10];

  float* out  = (float*)d_out;
  float* outh = out + (size_t)kT * kB * kV;          // 131,072,000
  float* outc = outh + (size_t)kL * kB * kH;         // +262,144

  const size_t SZ_WPACK = 67108864;   // L*2*4H*H bf16
  const size_t SZ_WCLS  = 65536000;   // V*H bf16
  const size_t SZ_X     = 8388608;    // T*B*H bf16
  const size_t SZ_H3A   = 8388608;    // T*B*H bf16
  const size_t SZ_HBUF  = 786432;     // 3 layers * 2 parity * B*H bf16
  const size_t SZ_HBI   = 524288;     // L*B*H bf16
  const size_t SZ_BSUM  = 65536;      // L*4H f32
  const size_t SZ_LOGZ  = 16384;      // T*B f32
  const size_t FULL_REQ = SZ_WPACK + SZ_WCLS + SZ_X + SZ_H3A + SZ_HBUF + SZ_HBI + SZ_BSUM + SZ_LOGZ;
  const bool full = (ws_size >= FULL_REQ);

  char* ws = (char*)d_ws;
  size_t off = 0;
  u16* wpack = (u16*)(ws + off); off += SZ_WPACK;
  u16* wclsb = nullptr;
  if (full) { wclsb = (u16*)(ws + off); off += SZ_WCLS; }
  u16*   X    = (u16*)(ws + off); off += SZ_X;
  u16*   h3a  = (u16*)(ws + off); off += SZ_H3A;
  u16*   hbuf = (u16*)(ws + off); off += SZ_HBUF;
  u16*   hbi  = (u16*)(ws + off); off += SZ_HBI;
  float* bsum = (float*)(ws + off); off += SZ_BSUM;
  float* logz = (float*)(ws + off); off += SZ_LOGZ;

  pack_lstm<<<16384, 256, 0, stream>>>(Wih, Whh, wpack);
  if (full) pack_cls<<<16000, 256, 0, stream>>>(Wcls, wclsb);
  pack_x   <<<2048,  256, 0, stream>>>(emb, tgt, X);
  pack_init<<<192,   256, 0, stream>>>(h0, bih, bhh, hbi, bsum);

  void* args[] = { (void*)&wpack, (void*)&X, (void*)&h3a, (void*)&hbuf, (void*)&hbi,
                   (void*)&bsum, (void*)&c0, (void*)&outh, (void*)&outc };
  hipLaunchCooperativeKernel((const void*)lstm_coop, dim3(256), dim3(512), args, 0, stream);

  if (full) cls_gemm    <<<dim3(250, 32), 256, 0, stream>>>(h3a, wclsb, bcls, out);
  else      cls_gemm_f32<<<dim3(250, 32), 256, 0, stream>>>(h3a, Wcls,  bcls, out);
  logz_k  <<<4096, 256, 0, stream>>>(out, logz);
  sub_k   <<<4096, 256, 0, stream>>>(out, logz);
}

// Round 3
// 2523.539 us; speedup vs baseline: 2.6294x; 2.6294x over previous
//
#include <hip/hip_runtime.h>

using u16 = unsigned short;
using u32 = unsigned int;

typedef __bf16 bf16x8 __attribute__((ext_vector_type(8)));
typedef float  f32x4  __attribute__((ext_vector_type(4)));
typedef u16    u16x8  __attribute__((ext_vector_type(8)));

static constexpr int kV = 32000, kH = 1024, kB = 64, kT = 64, kL = 4, kEOS = 2;

__device__ __forceinline__ u16 f2bf(float f) {
  u32 u = __float_as_uint(f);
  u = (u + 0x7fffu + ((u >> 16) & 1u)) >> 16;
  return (u16)u;
}
__device__ __forceinline__ float sigf(float x)   { return 1.0f / (1.0f + __expf(-x)); }
__device__ __forceinline__ float tanhf_(float x) { return 1.0f - 2.0f / (__expf(2.0f * x) + 1.0f); }

typedef const __attribute__((address_space(1))) u32* gas_ptr;
typedef __attribute__((address_space(3))) u32*       las_ptr;
__device__ __forceinline__ void async16(const u16* g, u16* l) {
  // LDS dest is wave-uniform base; HW writes base + lane*16B. Global src is per-lane.
  __builtin_amdgcn_global_load_lds((gas_ptr)g, (las_ptr)l, 16, 0, 0);
}

__device__ __forceinline__ void spin64(int* p) {
  while (__hip_atomic_load(p, __ATOMIC_RELAXED, __HIP_MEMORY_SCOPE_AGENT) < 64)
    __builtin_amdgcn_s_sleep(2);
}

// ---------------- prep kernels (unchanged layouts) ----------------

// wpack[blk(256)][mat(2)][kk(32)][cf(4)][lane(64)][8]
__global__ void pack_lstm(const float* __restrict__ Wih, const float* __restrict__ Whh,
                          u16* __restrict__ wpack) {
  const int cid  = blockIdx.x * 256 + threadIdx.x;   // < 4,194,304
  const int lane = cid & 63;
  const int cf   = (cid >> 6) & 3;
  const int kk   = (cid >> 8) & 31;
  const int mt   = (cid >> 13) & 1;
  const int blk  = cid >> 14;
  const int lay = blk >> 6, cb = blk & 63;
  const int wr = cf * 1024 + cb * 16 + (lane & 15);
  const int kb = kk * 32 + (lane >> 4) * 8;
  const float* src = (mt ? Whh : Wih) + ((size_t)lay * 4096 + wr) * 1024 + kb;
  const float4* s4 = (const float4*)src;
  float4 v0 = s4[0], v1 = s4[1];
  u16x8 r;
  r[0]=f2bf(v0.x); r[1]=f2bf(v0.y); r[2]=f2bf(v0.z); r[3]=f2bf(v0.w);
  r[4]=f2bf(v1.x); r[5]=f2bf(v1.y); r[6]=f2bf(v1.z); r[7]=f2bf(v1.w);
  *(u16x8*)(wpack + (size_t)cid * 8) = r;
}

__global__ void pack_cls(const float* __restrict__ W, u16* __restrict__ o) {
  const size_t cid = (size_t)blockIdx.x * 256 + threadIdx.x;  // < 4,096,000
  const float4* s4 = (const float4*)(W + cid * 8);
  float4 v0 = s4[0], v1 = s4[1];
  u16x8 r;
  r[0]=f2bf(v0.x); r[1]=f2bf(v0.y); r[2]=f2bf(v0.z); r[3]=f2bf(v0.w);
  r[4]=f2bf(v1.x); r[5]=f2bf(v1.y); r[6]=f2bf(v1.z); r[7]=f2bf(v1.w);
  *(u16x8*)(o + cid * 8) = r;
}

__global__ void pack_x(const float* __restrict__ emb, const int* __restrict__ tgt,
                       u16* __restrict__ X) {
  const int cid = blockIdx.x * 256 + threadIdx.x;    // < 524,288
  const int kc = cid & 127, b = (cid >> 7) & 63, t = cid >> 13;
  const int tok = (t == 0) ? kEOS : tgt[b * 64 + t - 1];
  const float4* s4 = (const float4*)(emb + (size_t)tok * 1024 + kc * 8);
  float4 v0 = s4[0], v1 = s4[1];
  u16x8 r;
  r[0]=f2bf(v0.x); r[1]=f2bf(v0.y); r[2]=f2bf(v0.z); r[3]=f2bf(v0.w);
  r[4]=f2bf(v1.x); r[5]=f2bf(v1.y); r[6]=f2bf(v1.z); r[7]=f2bf(v1.w);
  *(u16x8*)(X + (size_t)cid * 8) = r;
}

__global__ void pack_init(const float* __restrict__ h0, const float* __restrict__ bih,
                          const float* __restrict__ bhh, u16* __restrict__ hbinit,
                          float* __restrict__ bsum) {
  const int cid = blockIdx.x * 256 + threadIdx.x;    // grid = 192*256 = 49,152 exact
  if (cid < 32768) {
    const float4* s4 = (const float4*)(h0 + (size_t)cid * 8);
    float4 v0 = s4[0], v1 = s4[1];
    u16x8 r;
    r[0]=f2bf(v0.x); r[1]=f2bf(v0.y); r[2]=f2bf(v0.z); r[3]=f2bf(v0.w);
    r[4]=f2bf(v1.x); r[5]=f2bf(v1.y); r[6]=f2bf(v1.z); r[7]=f2bf(v1.w);
    *(u16x8*)(hbinit + (size_t)cid * 8) = r;
  } else {
    const int i = cid - 32768;   // < 16384 = L*4H
    bsum[i] = bih[i] + bhh[i];
  }
}

// ---------------- flag-synced recurrence, register-resident weights ----------------
// 256 blocks x 512 thr (co-resident via cooperative launch; no grid.sync).
// block: lay = blk>>6, 16 hidden units (64 gate cols). Waves (8):
//   staging role: (smat = w>>2, sm = w&3) -> stages A-frag sm of matrix smat each k-iter.
//   compute role: (cmat = w>>2, cwc = (w>>1)&1, ckh = w&1) -> N=32 cols (cwc half),
//                 k-iters with parity ckh; B-weights in 128 VGPRs for the whole kernel.
// Sync: cnt[lay][t] incremented by each of 64 blocks after h(lay,t) stored (release);
//       block (lay,t) spins on cnt[lay][t-1], cnt[lay-1][t], cnt[lay+1][t-2] (acquire).
__global__ void __launch_bounds__(512, 2)
lstm_coop(const u16* __restrict__ wpack, const u16* __restrict__ xall,
          u16* __restrict__ h3all, u16* __restrict__ hb,
          const u16* __restrict__ hbinit, const float* __restrict__ bsum,
          const float* __restrict__ c0, float* __restrict__ outh, float* __restrict__ outc,
          int* cnt) {
  __shared__ u16 stg[8][4096];       // 8-slot ring; slot = [mat(2)][frag m(4)][lane(64)][8] = 8 KB
  __shared__ float Gc[4][64][68];    // 4 partial copies (q = cmat*2+ckh), row=batch, col=gatecol, pad 68

  const int tid = threadIdx.x, lane = tid & 63, wave = tid >> 6;
  const int l15 = lane & 15, l4 = lane >> 4;
  const int smat = wave >> 2, sm = wave & 3;
  const int cmat = wave >> 2, cwc = (wave >> 1) & 1, ckh = wave & 1;
  const int blk = blockIdx.x, lay = blk >> 6, cb = blk & 63, u0 = cb << 4;
  const int ub = tid >> 3, uu = (tid & 7) * 2;

  // --- persistent state loads ---
  float creg0 = c0[((size_t)lay * 64 + ub) * 1024 + u0 + uu];
  float creg1 = c0[((size_t)lay * 64 + ub) * 1024 + u0 + uu + 1];
  float bsv[8];
  #pragma unroll
  for (int g = 0; g < 4; ++g) {
    bsv[g]     = bsum[lay * 4096 + g * 1024 + u0 + uu];
    bsv[4 + g] = bsum[lay * 4096 + g * 1024 + u0 + uu + 1];
  }

  // --- weights -> registers (held for all 64 steps): 2 col-frags x 16 k-iters ---
  const size_t wbase = (size_t)blk * 131072;
  bf16x8 breg[2][16];
  #pragma unroll
  for (int ci = 0; ci < 2; ++ci)
    #pragma unroll
    for (int j = 0; j < 16; ++j)
      breg[ci][j] = *(const bf16x8*)(wpack + wbase
          + (size_t)(((cmat * 32 + 2 * j + ckh) * 4) + cwc * 2 + ci) * 512 + lane * 8);

  #pragma unroll 1
  for (int t = 0; t < kT; ++t) {
    // --- dependency waits (tid0 spins; others park at barrier) ---
    if (tid == 0) {
      if (t >= 1)               spin64(&cnt[lay * 64 + (t - 1)]);
      if (lay >= 1)             spin64(&cnt[(lay - 1) * 64 + t]);
      if (lay <= 2 && t >= 2)   spin64(&cnt[(lay + 1) * 64 + (t - 2)]);
      __builtin_amdgcn_fence(__ATOMIC_ACQUIRE, "agent");   // invalidate L1/L2 before reading producers' data
    }
    __syncthreads();

    const u16* xsrc = (lay == 0) ? (xall + (size_t)t * 65536)
                                 : (hb + ((size_t)(lay - 1) * 2 + (t & 1)) * 65536);
    const u16* hsrc = (t == 0) ? (hbinit + (size_t)lay * 65536)
                    : ((lay == 3) ? (h3all + (size_t)(t - 1) * 65536)
                                  : (hb + ((size_t)lay * 2 + ((t - 1) & 1)) * 65536));
    const u16* gsrc = (smat ? hsrc : xsrc) + (size_t)(sm * 16 + l15) * 1024 + l4 * 8;
    u16* ldst = &stg[0][0] + (smat * 4 + sm) * 512;   // frag region, wave-uniform

    // --- staged MFMA over 32 k-iters, ring depth 6, single barrier/iter ---
    f32x4 acc[4][2] = {};
    #pragma unroll
    for (int pc = 0; pc < 6; ++pc) async16(gsrc + pc * 32, ldst + (pc & 7) * 4096);
    #pragma unroll
    for (int c = 0; c < 32; ++c) {
      if (c <= 25) async16(gsrc + (c + 6) * 32, ldst + ((c + 6) & 7) * 4096);
      if (c <= 25)      asm volatile("s_waitcnt vmcnt(6)" ::: "memory");
      else if (c == 26) asm volatile("s_waitcnt vmcnt(5)" ::: "memory");
      else if (c == 27) asm volatile("s_waitcnt vmcnt(4)" ::: "memory");
      else if (c == 28) asm volatile("s_waitcnt vmcnt(3)" ::: "memory");
      else if (c == 29) asm volatile("s_waitcnt vmcnt(2)" ::: "memory");
      else if (c == 30) asm volatile("s_waitcnt vmcnt(1)" ::: "memory");
      else              asm volatile("s_waitcnt vmcnt(0)" ::: "memory");
      __builtin_amdgcn_s_barrier();
      asm volatile("" ::: "memory");
      if ((c & 1) == ckh) {
        const u16* As = &stg[c & 7][cmat * 2048];
        bf16x8 a[4];
        #pragma unroll
        for (int m = 0; m < 4; ++m) a[m] = *(const bf16x8*)(As + m * 512 + lane * 8);
        #pragma unroll
        for (int m = 0; m < 4; ++m) {
          acc[m][0] = __builtin_amdgcn_mfma_f32_16x16x32_bf16(a[m], breg[0][c >> 1], acc[m][0], 0, 0, 0);
          acc[m][1] = __builtin_amdgcn_mfma_f32_16x16x32_bf16(a[m], breg[1][c >> 1], acc[m][1], 0, 0, 0);
        }
      }
    }

    // --- partial-sum reduction via 4 G copies ---
    {
      const int q = cmat * 2 + ckh;
      #pragma unroll
      for (int m = 0; m < 4; ++m)
        #pragma unroll
        for (int ci = 0; ci < 2; ++ci)
          #pragma unroll
          for (int r = 0; r < 4; ++r)
            Gc[q][m * 16 + l4 * 4 + r][cwc * 32 + ci * 16 + l15] = acc[m][ci][r];
    }
    __syncthreads();

    // --- cell update: thread = (batch ub, 2 units uu,uu+1) ---
    float2 sg[4];
    #pragma unroll
    for (int g = 0; g < 4; ++g) {
      float2 a2 = make_float2(0.f, 0.f);
      #pragma unroll
      for (int q = 0; q < 4; ++q) {
        const float2 v = *(const float2*)&Gc[q][ub][g * 16 + uu];
        a2.x += v.x; a2.y += v.y;
      }
      sg[g] = a2;
    }
    u16 hv[2];
    #pragma unroll
    for (int p = 0; p < 2; ++p) {
      const float gi = (p ? sg[0].y : sg[0].x) + bsv[p * 4 + 0];
      const float gf = (p ? sg[1].y : sg[1].x) + bsv[p * 4 + 1];
      const float gg = (p ? sg[2].y : sg[2].x) + bsv[p * 4 + 2];
      const float go = (p ? sg[3].y : sg[3].x) + bsv[p * 4 + 3];
      const float cr = (p == 0) ? creg0 : creg1;
      const float c2 = sigf(gf) * cr + sigf(gi) * tanhf_(gg);
      const float h2 = sigf(go) * tanhf_(c2);
      if (p == 0) creg0 = c2; else creg1 = c2;
      hv[p] = f2bf(h2);
      if (t == kT - 1) {
        outh[((size_t)lay * 64 + ub) * 1024 + u0 + uu + p] = h2;
        outc[((size_t)lay * 64 + ub) * 1024 + u0 + uu + p] = c2;
      }
    }
    const u32 hpair = (u32)hv[0] | ((u32)hv[1] << 16);
    u16* hdst = (lay == 3) ? (h3all + (size_t)t * 65536) : (hb + ((size_t)lay * 2 + (t & 1)) * 65536);
    *(u32*)(hdst + (size_t)ub * 1024 + u0 + uu) = hpair;

    // --- publish: all stores drained (syncthreads waits vmcnt0), then release + flag ---
    __syncthreads();
    if (tid == 0) {
      __builtin_amdgcn_fence(__ATOMIC_RELEASE, "agent");   // write back L2 -> LLC
      __hip_atomic_fetch_add(&cnt[lay * 64 + t], 1, __ATOMIC_RELAXED, __HIP_MEMORY_SCOPE_AGENT);
    }
  }
}

// ---------------- classifier GEMM (full path) ----------------
__global__ void __launch_bounds__(256)
cls_gemm(const u16* __restrict__ A, const u16* __restrict__ Bw,
         const float* __restrict__ bcls, float* __restrict__ out) {
  __shared__ u16 sA[2][4096], sB[2][4096];   // [khi4][row128][8]
  const int tid = threadIdx.x, lane = tid & 63, wave = tid >> 6;
  const int wm = wave >> 1, wc = wave & 1;
  const int l15 = lane & 15, l4 = lane >> 4;
  const int bn = blockIdx.x, bm = blockIdx.y;
  const u16* Ab = A  + (size_t)bm * 131072;
  const u16* Bb = Bw + (size_t)bn * 131072;

  auto STAGE = [&](int kk) {
    u16* dA = sA[kk & 1]; u16* dB = sB[kk & 1];
    #pragma unroll
    for (int q = 0; q < 4; ++q) {
      const int u = wave * 4 + q, v = u & 7;
      const u16* g = ((u < 8) ? Ab : Bb) + (size_t)((v & 1) * 64 + lane) * 1024 + kk * 32 + (v >> 1) * 8;
      async16(g, ((u < 8) ? dA : dB) + v * 512);
    }
  };

  f32x4 acc[4][4] = {};
  STAGE(0);
  for (int kk = 0; kk < 32; ++kk) {
    if (kk < 31) { STAGE(kk + 1); asm volatile("s_waitcnt vmcnt(4)" ::: "memory"); }
    else         asm volatile("s_waitcnt vmcnt(0)" ::: "memory");
    __builtin_amdgcn_s_barrier();
    asm volatile("" ::: "memory");
    const u16* aS = sA[kk & 1]; const u16* bS = sB[kk & 1];
    bf16x8 av[4], bv[4];
    #pragma unroll
    for (int mi = 0; mi < 4; ++mi) av[mi] = *(const bf16x8*)(aS + l4 * 1024 + (wm * 64 + mi * 16 + l15) * 8);
    #pragma unroll
    for (int ci = 0; ci < 4; ++ci) bv[ci] = *(const bf16x8*)(bS + l4 * 1024 + (wc * 64 + ci * 16 + l15) * 8);
    #pragma unroll
    for (int mi = 0; mi < 4; ++mi)
      #pragma unroll
      for (int ci = 0; ci < 4; ++ci)
        acc[mi][ci] = __builtin_amdgcn_mfma_f32_16x16x32_bf16(av[mi], bv[ci], acc[mi][ci], 0, 0, 0);
    asm volatile("" ::: "memory");
    __builtin_amdgcn_s_barrier();
  }
  #pragma unroll
  for (int ci = 0; ci < 4; ++ci) {
    const int col = bn * 128 + wc * 64 + ci * 16 + l15;
    const float bc = bcls[col];
    #pragma unroll
    for (int mi = 0; mi < 4; ++mi) {
      #pragma unroll
      for (int r = 0; r < 4; ++r) {
        const int row = bm * 128 + wm * 64 + mi * 16 + l4 * 4 + r;
        out[(size_t)row * 32000 + col] = acc[mi][ci][r] + bc;
      }
    }
  }
}

// ---------------- classifier GEMM (compact path): Bw f32, converted on the fly ----------------
__global__ void __launch_bounds__(256)
cls_gemm_f32(const u16* __restrict__ A, const float* __restrict__ Bw,
             const float* __restrict__ bcls, float* __restrict__ out) {
  __shared__ u16 sA[2][4096], sB[2][4096];
  const int tid = threadIdx.x, lane = tid & 63, wave = tid >> 6;
  const int wm = wave >> 1, wc = wave & 1;
  const int l15 = lane & 15, l4 = lane >> 4;
  const int bn = blockIdx.x, bm = blockIdx.y;
  const u16*  Ab = A  + (size_t)bm * 131072;
  const float* Bb = Bw + (size_t)bn * 131072;

  auto LOADB = [&](int kk, u16x8* rb) {
    #pragma unroll
    for (int q = 0; q < 2; ++q) {
      const int p = tid + q * 256, row = p & 127, khi = p >> 7;
      const float4* s4 = (const float4*)(Bb + (size_t)row * 1024 + kk * 32 + khi * 8);
      float4 v0 = s4[0], v1 = s4[1];
      u16x8 r;
      r[0]=f2bf(v0.x); r[1]=f2bf(v0.y); r[2]=f2bf(v0.z); r[3]=f2bf(v0.w);
      r[4]=f2bf(v1.x); r[5]=f2bf(v1.y); r[6]=f2bf(v1.z); r[7]=f2bf(v1.w);
      rb[q] = r;
    }
  };
  auto WRITEB = [&](int kk, const u16x8* rb) {
    u16* dB = sB[kk & 1];
    #pragma unroll
    for (int q = 0; q < 2; ++q) {
      const int p = tid + q * 256;
      *(u16x8*)(dB + p * 8) = rb[q];
    }
  };
  auto STAGE_A = [&](int kk) {
    u16* dA = sA[kk & 1];
    #pragma unroll
    for (int q = 0; q < 2; ++q) {
      const int v = wave * 2 + q;
      const u16* g = Ab + (size_t)((v & 1) * 64 + lane) * 1024 + kk * 32 + (v >> 1) * 8;
      async16(g, dA + v * 512);
    }
  };

  f32x4 acc[4][4] = {};
  {
    u16x8 rb[2];
    LOADB(0, rb); STAGE_A(0); WRITEB(0, rb);
  }
  for (int kk = 0; kk < 32; ++kk) {
    if (kk < 31) {
      u16x8 rb[2];
      LOADB(kk + 1, rb);
      STAGE_A(kk + 1);
      WRITEB(kk + 1, rb);
    } else {
      asm volatile("s_waitcnt vmcnt(0)" ::: "memory");
    }
    __builtin_amdgcn_s_barrier();
    asm volatile("" ::: "memory");
    const u16* aS = sA[kk & 1]; const u16* bS = sB[kk & 1];
    bf16x8 av[4], bv[4];
    #pragma unroll
    for (int mi = 0; mi < 4; ++mi) av[mi] = *(const bf16x8*)(aS + l4 * 1024 + (wm * 64 + mi * 16 + l15) * 8);
    #pragma unroll
    for (int ci = 0; ci < 4; ++ci) bv[ci] = *(const bf16x8*)(bS + l4 * 1024 + (wc * 64 + ci * 16 + l15) * 8);
    #pragma unroll
    for (int mi = 0; mi < 4; ++mi)
      #pragma unroll
      for (int ci = 0; ci < 4; ++ci)
        acc[mi][ci] = __builtin_amdgcn_mfma_f32_16x16x32_bf16(av[mi], bv[ci], acc[mi][ci], 0, 0, 0);
    asm volatile("" ::: "memory");
    __builtin_amdgcn_s_barrier();
  }
  #pragma unroll
  for (int ci = 0; ci < 4; ++ci) {
    const int col = bn * 128 + wc * 64 + ci * 16 + l15;
    const float bc = bcls[col];
    #pragma unroll
    for (int mi = 0; mi < 4; ++mi) {
      #pragma unroll
      for (int r = 0; r < 4; ++r) {
        const int row = bm * 128 + wm * 64 + mi * 16 + l4 * 4 + r;
        out[(size_t)row * 32000 + col] = acc[mi][ci][r] + bc;
      }
    }
  }
}

// ---------------- log-softmax ----------------
__global__ void __launch_bounds__(256)
logz_k(const float* __restrict__ out, float* __restrict__ logz) {
  __shared__ float red[256];
  const int r = blockIdx.x;
  const float* p = out + (size_t)r * 32000;
  float m = -3.0e38f;
  for (int v = threadIdx.x; v < 32000; v += 256) m = fmaxf(m, p[v]);
  red[threadIdx.x] = m; __syncthreads();
  for (int s2 = 128; s2 > 0; s2 >>= 1) {
    if ((int)threadIdx.x < s2) red[threadIdx.x] = fmaxf(red[threadIdx.x], red[threadIdx.x + s2]);
    __syncthreads();
  }
  m = red[0]; __syncthreads();
  float s = 0.0f;
  for (int v = threadIdx.x; v < 32000; v += 256) s += __expf(p[v] - m);
  red[threadIdx.x] = s; __syncthreads();
  for (int s2 = 128; s2 > 0; s2 >>= 1) {
    if ((int)threadIdx.x < s2) red[threadIdx.x] += red[threadIdx.x + s2];
    __syncthreads();
  }
  if (threadIdx.x == 0) logz[r] = m + logf(red[0]);
}

__global__ void __launch_bounds__(256)
sub_k(float* __restrict__ out, const float* __restrict__ logz) {
  const int r = blockIdx.x;
  const float z = logz[r];
  float* p = out + (size_t)r * 32000;
  for (int v = threadIdx.x; v < 32000; v += 256) p[v] -= z;
}

// ---------------- host ----------------
extern "C" void kernel_launch(void* const* d_in, const int* in_sizes, int n_in,
                              void* d_out, int out_size, void* d_ws, size_t ws_size,
                              hipStream_t stream) {
  (void)in_sizes; (void)n_in; (void)out_size;
  const int*   tgt  = (const int*)d_in[1];
  const float* h0   = (const float*)d_in[2];
  const float* c0   = (const float*)d_in[3];
  const float* emb  = (const float*)d_in[4];
  const float* Wih  = (const float*)d_in[5];
  const float* Whh  = (const float*)d_in[6];
  const float* bih  = (const float*)d_in[7];
  const float* bhh  = (const float*)d_in[8];
  const float* Wcls = (const float*)d_in[9];
  const float* bcls = (const float*)d_in[10];

  float* out  = (float*)d_out;
  float* outh = out + (size_t)kT * kB * kV;          // 131,072,000
  float* outc = outh + (size_t)kL * kB * kH;         // +262,144

  const size_t SZ_WPACK = 67108864;   // L*2*4H*H bf16
  const size_t SZ_WCLS  = 65536000;   // V*H bf16
  const size_t SZ_X     = 8388608;    // T*B*H bf16
  const size_t SZ_H3A   = 8388608;    // T*B*H bf16
  const size_t SZ_HBUF  = 786432;     // 3 layers * 2 parity * B*H bf16
  const size_t SZ_HBI   = 524288;     // L*B*H bf16
  const size_t SZ_BSUM  = 65536;      // L*4H f32
  const size_t SZ_LOGZ  = 16384;      // T*B f32
  const size_t SZ_CNT   = 1024;       // 4*64 int flags
  const size_t FULL_REQ = SZ_WPACK + SZ_WCLS + SZ_X + SZ_H3A + SZ_HBUF + SZ_HBI + SZ_BSUM + SZ_LOGZ + SZ_CNT;
  const bool full = (ws_size >= FULL_REQ);

  char* ws = (char*)d_ws;
  size_t off = 0;
  u16* wpack = (u16*)(ws + off); off += SZ_WPACK;
  u16* wclsb = nullptr;
  if (full) { wclsb = (u16*)(ws + off); off += SZ_WCLS; }
  u16*   X    = (u16*)(ws + off); off += SZ_X;
  u16*   h3a  = (u16*)(ws + off); off += SZ_H3A;
  u16*   hbuf = (u16*)(ws + off); off += SZ_HBUF;
  u16*   hbi  = (u16*)(ws + off); off += SZ_HBI;
  float* bsum = (float*)(ws + off); off += SZ_BSUM;
  float* logz = (float*)(ws + off); off += SZ_LOGZ;
  int*   cnt  = (int*)(ws + off);  off += SZ_CNT;

  pack_lstm<<<16384, 256, 0, stream>>>(Wih, Whh, wpack);
  if (full) pack_cls<<<16000, 256, 0, stream>>>(Wcls, wclsb);
  pack_x   <<<2048,  256, 0, stream>>>(emb, tgt, X);
  pack_init<<<192,   256, 0, stream>>>(h0, bih, bhh, hbi, bsum);
  hipMemsetAsync(cnt, 0, SZ_CNT, stream);

  void* args[] = { (void*)&wpack, (void*)&X, (void*)&h3a, (void*)&hbuf, (void*)&hbi,
                   (void*)&bsum, (void*)&c0, (void*)&outh, (void*)&outc, (void*)&cnt };
  hipLaunchCooperativeKernel((const void*)lstm_coop, dim3(256), dim3(512), args, 0, stream);

  if (full) cls_gemm    <<<dim3(250, 32), 256, 0, stream>>>(h3a, wclsb, bcls, out);
  else      cls_gemm_f32<<<dim3(250, 32), 256, 0, stream>>>(h3a, Wcls,  bcls, out);
  logz_k  <<<4096, 256, 0, stream>>>(out, logz);
  sub_k   <<<4096, 256, 0, stream>>>(out, logz);
}

// Round 5
// 1753.907 us; speedup vs baseline: 3.7832x; 1.4388x over previous
//
#include <hip/hip_runtime.h>

using u16 = unsigned short;
using u32 = unsigned int;

typedef __bf16 bf16x8 __attribute__((ext_vector_type(8)));
typedef float  f32x4  __attribute__((ext_vector_type(4)));
typedef u16    u16x8  __attribute__((ext_vector_type(8)));

static constexpr int kV = 32000, kH = 1024, kB = 64, kT = 64, kL = 4, kEOS = 2;

__device__ __forceinline__ u16 f2bf(float f) {
  u32 u = __float_as_uint(f);
  u = (u + 0x7fffu + ((u >> 16) & 1u)) >> 16;
  return (u16)u;
}
__device__ __forceinline__ float sigf(float x)   { return 1.0f / (1.0f + __expf(-x)); }
__device__ __forceinline__ float tanhf_(float x) { return 1.0f - 2.0f / (__expf(2.0f * x) + 1.0f); }

typedef const __attribute__((address_space(1))) u32* gas_ptr;
typedef __attribute__((address_space(3))) u32*       las_ptr;
__device__ __forceinline__ void async16(const u16* g, u16* l) {
  // LDS dest is wave-uniform base; HW writes base + lane*16B. Global src is per-lane.
  __builtin_amdgcn_global_load_lds((gas_ptr)g, (las_ptr)l, 16, 0, 0);
}

__device__ __forceinline__ void spin64(int* p) {
  while (__hip_atomic_load(p, __ATOMIC_RELAXED, __HIP_MEMORY_SCOPE_AGENT) < 64)
    __builtin_amdgcn_s_sleep(1);
}

// Frag-packed 64x1024 bf16 matrix: [mtile=b>>4][ks=k>>5][lane=((k>>3)&3)*16+(b&15)][elem=k&7]
__device__ __forceinline__ size_t packed_off(int b, int k) {
  return (size_t)(((b >> 4) * 32 + (k >> 5)) * 512 + (((k >> 3) & 3) * 16 + (b & 15)) * 8 + (k & 7));
}

// ---------------- prep kernels ----------------

// wpack[blk(256)][mat(2)][kk(32)][cf(4)][lane(64)][8]
__global__ void pack_lstm(const float* __restrict__ Wih, const float* __restrict__ Whh,
                          u16* __restrict__ wpack) {
  const int cid  = blockIdx.x * 256 + threadIdx.x;   // < 4,194,304
  const int lane = cid & 63;
  const int cf   = (cid >> 6) & 3;
  const int kk   = (cid >> 8) & 31;
  const int mt   = (cid >> 13) & 1;
  const int blk  = cid >> 14;
  const int lay = blk >> 6, cb = blk & 63;
  const int wr = cf * 1024 + cb * 16 + (lane & 15);
  const int kb = kk * 32 + (lane >> 4) * 8;
  const float* src = (mt ? Whh : Wih) + ((size_t)lay * 4096 + wr) * 1024 + kb;
  const float4* s4 = (const float4*)src;
  float4 v0 = s4[0], v1 = s4[1];
  u16x8 r;
  r[0]=f2bf(v0.x); r[1]=f2bf(v0.y); r[2]=f2bf(v0.z); r[3]=f2bf(v0.w);
  r[4]=f2bf(v1.x); r[5]=f2bf(v1.y); r[6]=f2bf(v1.z); r[7]=f2bf(v1.w);
  *(u16x8*)(wpack + (size_t)cid * 8) = r;
}

__global__ void pack_cls(const float* __restrict__ W, u16* __restrict__ o) {
  const size_t cid = (size_t)blockIdx.x * 256 + threadIdx.x;  // < 4,096,000
  const float4* s4 = (const float4*)(W + cid * 8);
  float4 v0 = s4[0], v1 = s4[1];
  u16x8 r;
  r[0]=f2bf(v0.x); r[1]=f2bf(v0.y); r[2]=f2bf(v0.z); r[3]=f2bf(v0.w);
  r[4]=f2bf(v1.x); r[5]=f2bf(v1.y); r[6]=f2bf(v1.z); r[7]=f2bf(v1.w);
  *(u16x8*)(o + cid * 8) = r;
}

// X[t] frag-packed
__global__ void pack_x(const float* __restrict__ emb, const int* __restrict__ tgt,
                       u16* __restrict__ X) {
  const int cid = blockIdx.x * 256 + threadIdx.x;    // < 524,288
  const int kc = cid & 127, b = (cid >> 7) & 63, t = cid >> 13;
  const int tok = (t == 0) ? kEOS : tgt[b * 64 + t - 1];
  const float4* s4 = (const float4*)(emb + (size_t)tok * 1024 + kc * 8);
  float4 v0 = s4[0], v1 = s4[1];
  u16x8 r;
  r[0]=f2bf(v0.x); r[1]=f2bf(v0.y); r[2]=f2bf(v0.z); r[3]=f2bf(v0.w);
  r[4]=f2bf(v1.x); r[5]=f2bf(v1.y); r[6]=f2bf(v1.z); r[7]=f2bf(v1.w);
  *(u16x8*)(X + (size_t)t * 65536 + packed_off(b, kc * 8)) = r;
}

// hbinit frag-packed; bsum
__global__ void pack_init(const float* __restrict__ h0, const float* __restrict__ bih,
                          const float* __restrict__ bhh, u16* __restrict__ hbinit,
                          float* __restrict__ bsum) {
  const int cid = blockIdx.x * 256 + threadIdx.x;    // grid = 192*256 = 49,152 exact
  if (cid < 32768) {
    const int kc = cid & 127, row = cid >> 7;        // row = lay*64 + b
    const int lay = row >> 6, b = row & 63;
    const float4* s4 = (const float4*)(h0 + (size_t)cid * 8);
    float4 v0 = s4[0], v1 = s4[1];
    u16x8 r;
    r[0]=f2bf(v0.x); r[1]=f2bf(v0.y); r[2]=f2bf(v0.z); r[3]=f2bf(v0.w);
    r[4]=f2bf(v1.x); r[5]=f2bf(v1.y); r[6]=f2bf(v1.z); r[7]=f2bf(v1.w);
    *(u16x8*)(hbinit + (size_t)lay * 65536 + packed_off(b, kc * 8)) = r;
  } else {
    const int i = cid - 32768;   // < 16384 = L*4H
    bsum[i] = bih[i] + bhh[i];
  }
}

// ---------------- flag-synced recurrence ----------------
// 256 blocks x 512 thr (cooperative for co-residency; no grid.sync).
// block: lay = blk>>6, 16 hidden units (64 gate cols).
// Wave roles: cmat = w>>2 (0: x@Wi^T, 1: h@Wh^T), cwc = (w>>1)&1 (col half),
//             ckh = w&1 (k-slice parity). B-weights: 128 VGPRs, loaded once.
// K in 8 chunks of 128 (4 MFMA k-slices each; 8*4 = all 32 slices),
// triple-buffered LDS, 2-deep prefetch, counted vmcnt.
__global__ void __launch_bounds__(512)
lstm_coop(const u16* __restrict__ wpack, const u16* __restrict__ xall,
          u16* __restrict__ h3all, u16* __restrict__ hb,
          const u16* __restrict__ hbinit, const float* __restrict__ bsum,
          const float* __restrict__ c0, float* __restrict__ outh, float* __restrict__ outc,
          int* cnt) {
  __shared__ u16 stg[3][32][512];    // [buf][mat*16 + mtile*4 + ksl][lane*8]  = 96 KB
  __shared__ float Gc[2][64][68];    // partial gates by cmat; padded          = 34.8 KB

  const int tid = threadIdx.x, lane = tid & 63, wave = tid >> 6;
  const int l15 = lane & 15, l4 = lane >> 4;
  const int cmat = wave >> 2, cwc = (wave >> 1) & 1, ckh = wave & 1;
  const int blk = blockIdx.x, lay = blk >> 6, cb = blk & 63, u0 = cb << 4;
  const int ub = tid >> 3, uu = (tid & 7) * 2;

  float creg0 = c0[((size_t)lay * 64 + ub) * 1024 + u0 + uu];
  float creg1 = c0[((size_t)lay * 64 + ub) * 1024 + u0 + uu + 1];
  float bsv[8];
  #pragma unroll
  for (int g = 0; g < 4; ++g) {
    bsv[g]     = bsum[lay * 4096 + g * 1024 + u0 + uu];
    bsv[4 + g] = bsum[lay * 4096 + g * 1024 + u0 + uu + 1];
  }

  // weights -> registers: 2 col-frags x 16 k-slice pairs (parity ckh), 128 VGPRs.
  // breg[ci][j] holds global k-slice kk = 2*j + ckh.
  const size_t wbase = (size_t)blk * 131072;
  bf16x8 breg[2][16];
  #pragma unroll
  for (int ci = 0; ci < 2; ++ci)
    #pragma unroll
    for (int j = 0; j < 16; ++j)
      breg[ci][j] = *(const bf16x8*)(wpack + wbase
          + (size_t)(((cmat * 32 + 2 * j + ckh) * 4) + cwc * 2 + ci) * 512 + lane * 8);

  #pragma unroll 1
  for (int t = 0; t < kT; ++t) {
    // --- dependency waits: 3 parallel spinners, then one acquire (L1/L2 inv) ---
    if (tid < 3) {
      int idx = -1;
      if (tid == 0 && t >= 1)              idx = lay * 64 + (t - 1);
      if (tid == 1 && lay >= 1)            idx = (lay - 1) * 64 + t;
      if (tid == 2 && lay <= 2 && t >= 2)  idx = (lay + 1) * 64 + (t - 2);
      if (idx >= 0) spin64(&cnt[idx]);
    }
    __syncthreads();
    if (tid == 0) __builtin_amdgcn_fence(__ATOMIC_ACQUIRE, "agent");
    __syncthreads();

    const u16* xsrc = (lay == 0) ? (xall + (size_t)t * 65536)
                                 : (hb + ((size_t)(lay - 1) * 2 + (t & 1)) * 65536);
    const u16* hsrc = (t == 0) ? (hbinit + (size_t)lay * 65536)
                    : ((lay == 3) ? (h3all + (size_t)(t - 1) * 65536)
                                  : (hb + ((size_t)lay * 2 + ((t - 1) & 1)) * 65536));

    auto STAGE = [&](int c) {   // stage k-chunk c (32 KB): 8 waves x 4 linear 1KB tiles
      #pragma unroll
      for (int q = 0; q < 4; ++q) {
        const int j = wave * 4 + q;
        const int m2 = j >> 4, mt = (j >> 2) & 3, ksl = j & 3;   // global ks = c*4 + ksl
        const u16* g = (m2 ? hsrc : xsrc) + (size_t)((mt * 32 + c * 4 + ksl) * 512) + lane * 8;
        async16(g, &stg[c % 3][m2 * 16 + mt * 4 + ksl][0]);
      }
    };

    f32x4 acc[4][2] = {};
    STAGE(0); STAGE(1);
    #pragma unroll
    for (int c = 0; c < 8; ++c) {
      if (c < 7) asm volatile("s_waitcnt vmcnt(4)" ::: "memory");
      else       asm volatile("s_waitcnt vmcnt(0)" ::: "memory");
      __builtin_amdgcn_s_barrier();
      asm volatile("" ::: "memory");
      if (c < 6) STAGE(c + 2);
      const u16* As = &stg[c % 3][cmat * 16][0];
      #pragma unroll
      for (int s = 0; s < 2; ++s) {
        const int ksl = 2 * s + ckh;            // global ks = 4c + 2s + ckh = 2*(2c+s)+ckh
        bf16x8 a[4];
        #pragma unroll
        for (int m = 0; m < 4; ++m)
          a[m] = *(const bf16x8*)(As + (m * 4 + ksl) * 512 + lane * 8);
        #pragma unroll
        for (int m = 0; m < 4; ++m) {
          acc[m][0] = __builtin_amdgcn_mfma_f32_16x16x32_bf16(a[m], breg[0][2 * c + s], acc[m][0], 0, 0, 0);
          acc[m][1] = __builtin_amdgcn_mfma_f32_16x16x32_bf16(a[m], breg[1][2 * c + s], acc[m][1], 0, 0, 0);
        }
      }
    }

    // --- two-phase partial-gate reduction into Gc[cmat] ---
    if (ckh == 0) {
      #pragma unroll
      for (int m = 0; m < 4; ++m)
        #pragma unroll
        for (int ci = 0; ci < 2; ++ci)
          #pragma unroll
          for (int r = 0; r < 4; ++r)
            Gc[cmat][m * 16 + l4 * 4 + r][cwc * 32 + ci * 16 + l15] = acc[m][ci][r];
    }
    __syncthreads();
    if (ckh == 1) {
      #pragma unroll
      for (int m = 0; m < 4; ++m)
        #pragma unroll
        for (int ci = 0; ci < 2; ++ci)
          #pragma unroll
          for (int r = 0; r < 4; ++r)
            Gc[cmat][m * 16 + l4 * 4 + r][cwc * 32 + ci * 16 + l15] += acc[m][ci][r];
    }
    __syncthreads();

    // --- cell update: thread = (batch ub, units uu,uu+1) ---
    float2 sg[4];
    #pragma unroll
    for (int g = 0; g < 4; ++g) {
      const int col = g * 16 + uu;
      const float2 v0 = *(const float2*)&Gc[0][ub][col];
      const float2 v1 = *(const float2*)&Gc[1][ub][col];
      sg[g] = make_float2(v0.x + v1.x, v0.y + v1.y);
    }
    u16 hv[2];
    #pragma unroll
    for (int p = 0; p < 2; ++p) {
      const float gi = (p ? sg[0].y : sg[0].x) + bsv[p * 4 + 0];
      const float gf = (p ? sg[1].y : sg[1].x) + bsv[p * 4 + 1];
      const float gg = (p ? sg[2].y : sg[2].x) + bsv[p * 4 + 2];
      const float go = (p ? sg[3].y : sg[3].x) + bsv[p * 4 + 3];
      const float cr = (p == 0) ? creg0 : creg1;
      const float c2 = sigf(gf) * cr + sigf(gi) * tanhf_(gg);
      const float h2 = sigf(go) * tanhf_(c2);
      if (p == 0) creg0 = c2; else creg1 = c2;
      hv[p] = f2bf(h2);
      if (t == kT - 1) {
        outh[((size_t)lay * 64 + ub) * 1024 + u0 + uu + p] = h2;
        outc[((size_t)lay * 64 + ub) * 1024 + u0 + uu + p] = c2;
      }
    }
    // publish h in frag-packed layout, agent-scope (visible at coherence point on retire)
    const u32 hpair = (u32)hv[0] | ((u32)hv[1] << 16);
    u16* hbase = (lay == 3) ? (h3all + (size_t)t * 65536)
                            : (hb + ((size_t)lay * 2 + (t & 1)) * 65536);
    u32* hdst = (u32*)(hbase + packed_off(ub, u0 + uu));
    __hip_atomic_store(hdst, hpair, __ATOMIC_RELAXED, __HIP_MEMORY_SCOPE_AGENT);

    // __syncthreads drains vmcnt(0): all agent-scope stores complete before flag
    __syncthreads();
    if (tid == 0)
      __hip_atomic_fetch_add(&cnt[lay * 64 + t], 1, __ATOMIC_RELAXED, __HIP_MEMORY_SCOPE_AGENT);
  }
}

// ---------------- classifier GEMM (full path): A frag-packed, Bw pre-packed bf16 ----------------
__global__ void __launch_bounds__(256)
cls_gemm(const u16* __restrict__ A, const u16* __restrict__ Bw,
         const float* __restrict__ bcls, float* __restrict__ out) {
  __shared__ u16 sA[2][4096], sB[2][4096];
  const int tid = threadIdx.x, lane = tid & 63, wave = tid >> 6;
  const int wm = wave >> 1, wc = wave & 1;
  const int l15 = lane & 15, l4 = lane >> 4;
  const int bn = blockIdx.x, bm = blockIdx.y;
  const u16* Ab = A  + (size_t)bm * 131072;   // two packed 64x1024 t-matrices
  const u16* Bb = Bw + (size_t)bn * 131072;

  auto STAGE = [&](int kk) {
    u16* dA = sA[kk & 1]; u16* dB = sB[kk & 1];
    #pragma unroll
    for (int q = 0; q < 4; ++q) {
      const int u = wave * 4 + q;
      if (u < 8) {  // A: tiles [tq=u>>2][mtile=u&3] at k-slice kk (packed, linear)
        const u16* g = Ab + (size_t)(u >> 2) * 65536 + (size_t)(((u & 3) * 32 + kk) * 512) + lane * 8;
        async16(g, dA + u * 512);
      } else {      // B: row-major staging
        const int v = u & 7;
        const u16* g = Bb + (size_t)((v & 1) * 64 + lane) * 1024 + kk * 32 + (v >> 1) * 8;
        async16(g, dB + v * 512);
      }
    }
  };

  f32x4 acc[4][4] = {};
  STAGE(0);
  for (int kk = 0; kk < 32; ++kk) {
    if (kk < 31) { STAGE(kk + 1); asm volatile("s_waitcnt vmcnt(4)" ::: "memory"); }
    else         asm volatile("s_waitcnt vmcnt(0)" ::: "memory");
    __builtin_amdgcn_s_barrier();
    asm volatile("" ::: "memory");
    const u16* aS = sA[kk & 1]; const u16* bS = sB[kk & 1];
    bf16x8 av[4], bv[4];
    #pragma unroll
    for (int mi = 0; mi < 4; ++mi) av[mi] = *(const bf16x8*)(aS + (wm * 4 + mi) * 512 + lane * 8);
    #pragma unroll
    for (int ci = 0; ci < 4; ++ci) bv[ci] = *(const bf16x8*)(bS + l4 * 1024 + (wc * 64 + ci * 16 + l15) * 8);
    #pragma unroll
    for (int mi = 0; mi < 4; ++mi)
      #pragma unroll
      for (int ci = 0; ci < 4; ++ci)
        acc[mi][ci] = __builtin_amdgcn_mfma_f32_16x16x32_bf16(av[mi], bv[ci], acc[mi][ci], 0, 0, 0);
    asm volatile("" ::: "memory");
    __builtin_amdgcn_s_barrier();
  }
  #pragma unroll
  for (int ci = 0; ci < 4; ++ci) {
    const int col = bn * 128 + wc * 64 + ci * 16 + l15;
    const float bc = bcls[col];
    #pragma unroll
    for (int mi = 0; mi < 4; ++mi) {
      #pragma unroll
      for (int r = 0; r < 4; ++r) {
        const int row = bm * 128 + wm * 64 + mi * 16 + l4 * 4 + r;
        out[(size_t)row * 32000 + col] = acc[mi][ci][r] + bc;
      }
    }
  }
}

// ---------------- classifier GEMM (compact path): Bw f32 converted on the fly ----------------
__global__ void __launch_bounds__(256)
cls_gemm_f32(const u16* __restrict__ A, const float* __restrict__ Bw,
             const float* __restrict__ bcls, float* __restrict__ out) {
  __shared__ u16 sA[2][4096], sB[2][4096];
  const int tid = threadIdx.x, lane = tid & 63, wave = tid >> 6;
  const int wm = wave >> 1, wc = wave & 1;
  const int l15 = lane & 15, l4 = lane >> 4;
  const int bn = blockIdx.x, bm = blockIdx.y;
  const u16*  Ab = A  + (size_t)bm * 131072;
  const float* Bb = Bw + (size_t)bn * 131072;

  auto LOADB = [&](int kk, u16x8* rb) {
    #pragma unroll
    for (int q = 0; q < 2; ++q) {
      const int p = tid + q * 256, row = p & 127, khi = p >> 7;
      const float4* s4 = (const float4*)(Bb + (size_t)row * 1024 + kk * 32 + khi * 8);
      float4 v0 = s4[0], v1 = s4[1];
      u16x8 r;
      r[0]=f2bf(v0.x); r[1]=f2bf(v0.y); r[2]=f2bf(v0.z); r[3]=f2bf(v0.w);
      r[4]=f2bf(v1.x); r[5]=f2bf(v1.y); r[6]=f2bf(v1.z); r[7]=f2bf(v1.w);
      rb[q] = r;
    }
  };
  auto WRITEB = [&](int kk, const u16x8* rb) {
    u16* dB = sB[kk & 1];
    #pragma unroll
    for (int q = 0; q < 2; ++q) {
      const int p = tid + q * 256;
      *(u16x8*)(dB + p * 8) = rb[q];
    }
  };
  auto STAGE_A = [&](int kk) {
    u16* dA = sA[kk & 1];
    #pragma unroll
    for (int q = 0; q < 2; ++q) {
      const int v = wave * 2 + q;
      const u16* g = Ab + (size_t)(v >> 2) * 65536 + (size_t)(((v & 3) * 32 + kk) * 512) + lane * 8;
      async16(g, dA + v * 512);
    }
  };

  f32x4 acc[4][4] = {};
  {
    u16x8 rb[2];
    LOADB(0, rb); STAGE_A(0); WRITEB(0, rb);
  }
  for (int kk = 0; kk < 32; ++kk) {
    if (kk < 31) {
      u16x8 rb[2];
      LOADB(kk + 1, rb);
      STAGE_A(kk + 1);
      WRITEB(kk + 1, rb);
    } else {
      asm volatile("s_waitcnt vmcnt(0)" ::: "memory");
    }
    __builtin_amdgcn_s_barrier();
    asm volatile("" ::: "memory");
    const u16* aS = sA[kk & 1]; const u16* bS = sB[kk & 1];
    bf16x8 av[4], bv[4];
    #pragma unroll
    for (int mi = 0; mi < 4; ++mi) av[mi] = *(const bf16x8*)(aS + (wm * 4 + mi) * 512 + lane * 8);
    #pragma unroll
    for (int ci = 0; ci < 4; ++ci) bv[ci] = *(const bf16x8*)(bS + l4 * 1024 + (wc * 64 + ci * 16 + l15) * 8);
    #pragma unroll
    for (int mi = 0; mi < 4; ++mi)
      #pragma unroll
      for (int ci = 0; ci < 4; ++ci)
        acc[mi][ci] = __builtin_amdgcn_mfma_f32_16x16x32_bf16(av[mi], bv[ci], acc[mi][ci], 0, 0, 0);
    asm volatile("" ::: "memory");
    __builtin_amdgcn_s_barrier();
  }
  #pragma unroll
  for (int ci = 0; ci < 4; ++ci) {
    const int col = bn * 128 + wc * 64 + ci * 16 + l15;
    const float bc = bcls[col];
    #pragma unroll
    for (int mi = 0; mi < 4; ++mi) {
      #pragma unroll
      for (int r = 0; r < 4; ++r) {
        const int row = bm * 128 + wm * 64 + mi * 16 + l4 * 4 + r;
        out[(size_t)row * 32000 + col] = acc[mi][ci][r] + bc;
      }
    }
  }
}

// ---------------- fused log-softmax ----------------
__global__ void __launch_bounds__(256)
lsm_k(float* __restrict__ out) {
  __shared__ float red[256];
  const int r = blockIdx.x;
  float* p = out + (size_t)r * 32000;
  const float4* p4 = (const float4*)p;
  float m = -3.0e38f;
  for (int v = threadIdx.x; v < 8000; v += 256) {
    const float4 x = p4[v];
    m = fmaxf(m, fmaxf(fmaxf(x.x, x.y), fmaxf(x.z, x.w)));
  }
  red[threadIdx.x] = m; __syncthreads();
  for (int s2 = 128; s2 > 0; s2 >>= 1) {
    if ((int)threadIdx.x < s2) red[threadIdx.x] = fmaxf(red[threadIdx.x], red[threadIdx.x + s2]);
    __syncthreads();
  }
  m = red[0]; __syncthreads();
  float s = 0.0f;
  for (int v = threadIdx.x; v < 8000; v += 256) {
    const float4 x = p4[v];
    s += __expf(x.x - m) + __expf(x.y - m) + __expf(x.z - m) + __expf(x.w - m);
  }
  red[threadIdx.x] = s; __syncthreads();
  for (int s2 = 128; s2 > 0; s2 >>= 1) {
    if ((int)threadIdx.x < s2) red[threadIdx.x] += red[threadIdx.x + s2];
    __syncthreads();
  }
  const float z = m + logf(red[0]);
  float4* q4 = (float4*)p;
  for (int v = threadIdx.x; v < 8000; v += 256) {
    float4 x = p4[v];
    x.x -= z; x.y -= z; x.z -= z; x.w -= z;
    q4[v] = x;
  }
}

// ---------------- host ----------------
extern "C" void kernel_launch(void* const* d_in, const int* in_sizes, int n_in,
                              void* d_out, int out_size, void* d_ws, size_t ws_size,
                              hipStream_t stream) {
  (void)in_sizes; (void)n_in; (void)out_size;
  const int*   tgt  = (const int*)d_in[1];
  const float* h0   = (const float*)d_in[2];
  const float* c0   = (const float*)d_in[3];
  const float* emb  = (const float*)d_in[4];
  const float* Wih  = (const float*)d_in[5];
  const float* Whh  = (const float*)d_in[6];
  const float* bih  = (const float*)d_in[7];
  const float* bhh  = (const float*)d_in[8];
  const float* Wcls = (const float*)d_in[9];
  const float* bcls = (const float*)d_in[10];

  float* out  = (float*)d_out;
  float* outh = out + (size_t)kT * kB * kV;          // 131,072,000
  float* outc = outh + (size_t)kL * kB * kH;         // +262,144

  const size_t SZ_WPACK = 67108864;   // L*2*4H*H bf16
  const size_t SZ_WCLS  = 65536000;   // V*H bf16
  const size_t SZ_X     = 8388608;    // T*B*H bf16 (frag-packed)
  const size_t SZ_H3A   = 8388608;    // T*B*H bf16 (frag-packed)
  const size_t SZ_HBUF  = 786432;     // 3 layers * 2 parity * B*H bf16 (frag-packed)
  const size_t SZ_HBI   = 524288;     // L*B*H bf16 (frag-packed)
  const size_t SZ_BSUM  = 65536;      // L*4H f32
  const size_t SZ_CNT   = 1024;       // 4*64 int flags
  const size_t FULL_REQ = SZ_WPACK + SZ_WCLS + SZ_X + SZ_H3A + SZ_HBUF + SZ_HBI + SZ_BSUM + SZ_CNT;
  const bool full = (ws_size >= FULL_REQ);

  char* ws = (char*)d_ws;
  size_t off = 0;
  u16* wpack = (u16*)(ws + off); off += SZ_WPACK;
  u16* wclsb = nullptr;
  if (full) { wclsb = (u16*)(ws + off); off += SZ_WCLS; }
  u16*   X    = (u16*)(ws + off); off += SZ_X;
  u16*   h3a  = (u16*)(ws + off); off += SZ_H3A;
  u16*   hbuf = (u16*)(ws + off); off += SZ_HBUF;
  u16*   hbi  = (u16*)(ws + off); off += SZ_HBI;
  float* bsum = (float*)(ws + off); off += SZ_BSUM;
  int*   cnt  = (int*)(ws + off);  off += SZ_CNT;

  pack_lstm<<<16384, 256, 0, stream>>>(Wih, Whh, wpack);
  if (full) pack_cls<<<16000, 256, 0, stream>>>(Wcls, wclsb);
  pack_x   <<<2048,  256, 0, stream>>>(emb, tgt, X);
  pack_init<<<192,   256, 0, stream>>>(h0, bih, bhh, hbi, bsum);
  hipMemsetAsync(cnt, 0, SZ_CNT, stream);

  void* args[] = { (void*)&wpack, (void*)&X, (void*)&h3a, (void*)&hbuf, (void*)&hbi,
                   (void*)&bsum, (void*)&c0, (void*)&outh, (void*)&outc, (void*)&cnt };
  hipLaunchCooperativeKernel((const void*)lstm_coop, dim3(256), dim3(512), args, 0, stream);

  if (full) cls_gemm    <<<dim3(250, 32), 256, 0, stream>>>(h3a, wclsb, bcls, out);
  else      cls_gemm_f32<<<dim3(250, 32), 256, 0, stream>>>(h3a, Wcls,  bcls, out);
  lsm_k<<<4096, 256, 0, stream>>>(out);
}

// Round 6
// 1450.536 us; speedup vs baseline: 4.5745x; 1.2091x over previous
//
#include <hip/hip_runtime.h>

using u16 = unsigned short;
using u32 = unsigned int;

typedef __bf16 bf16x8 __attribute__((ext_vector_type(8)));
typedef float  f32x4  __attribute__((ext_vector_type(4)));
typedef u16    u16x8  __attribute__((ext_vector_type(8)));

static constexpr int kV = 32000, kH = 1024, kB = 64, kT = 64, kL = 4, kEOS = 2;

struct Flag { int v; int pad[15]; };   // one 64B line per flag: no write contention

__device__ __forceinline__ u16 f2bf(float f) {
  u32 u = __float_as_uint(f);
  u = (u + 0x7fffu + ((u >> 16) & 1u)) >> 16;
  return (u16)u;
}
__device__ __forceinline__ float sigf(float x)   { return 1.0f / (1.0f + __expf(-x)); }
__device__ __forceinline__ float tanhf_(float x) { return 1.0f - 2.0f / (__expf(2.0f * x) + 1.0f); }

typedef const __attribute__((address_space(1))) u32* gas_ptr;
typedef __attribute__((address_space(3))) u32*       las_ptr;
__device__ __forceinline__ void async16(const u16* g, u16* l) {
  // LDS dest is wave-uniform base; HW writes base + lane*16B. Global src is per-lane.
  __builtin_amdgcn_global_load_lds((gas_ptr)g, (las_ptr)l, 16, 0, 0);
}

__device__ __forceinline__ void spin_ge(const int* p, int tgt) {
  while (__hip_atomic_load(p, __ATOMIC_RELAXED, __HIP_MEMORY_SCOPE_AGENT) < tgt)
    __builtin_amdgcn_s_sleep(2);
}

// Frag-packed 64x1024 bf16 matrix: [mtile=b>>4][ks=k>>5][lane=((k>>3)&3)*16+(b&15)][elem=k&7]
__device__ __forceinline__ size_t packed_off(int b, int k) {
  return (size_t)(((b >> 4) * 32 + (k >> 5)) * 512 + (((k >> 3) & 3) * 16 + (b & 15)) * 8 + (k & 7));
}

// ---------------- prep kernels ----------------

// wpack[blk(256)][mat(2)][kk(32)][cf(4)][lane(64)][8]
__global__ void pack_lstm(const float* __restrict__ Wih, const float* __restrict__ Whh,
                          u16* __restrict__ wpack) {
  const int cid  = blockIdx.x * 256 + threadIdx.x;   // < 4,194,304
  const int lane = cid & 63;
  const int cf   = (cid >> 6) & 3;
  const int kk   = (cid >> 8) & 31;
  const int mt   = (cid >> 13) & 1;
  const int blk  = cid >> 14;
  const int lay = blk >> 6, cb = blk & 63;
  const int wr = cf * 1024 + cb * 16 + (lane & 15);
  const int kb = kk * 32 + (lane >> 4) * 8;
  const float* src = (mt ? Whh : Wih) + ((size_t)lay * 4096 + wr) * 1024 + kb;
  const float4* s4 = (const float4*)src;
  float4 v0 = s4[0], v1 = s4[1];
  u16x8 r;
  r[0]=f2bf(v0.x); r[1]=f2bf(v0.y); r[2]=f2bf(v0.z); r[3]=f2bf(v0.w);
  r[4]=f2bf(v1.x); r[5]=f2bf(v1.y); r[6]=f2bf(v1.z); r[7]=f2bf(v1.w);
  *(u16x8*)(wpack + (size_t)cid * 8) = r;
}

__global__ void pack_cls(const float* __restrict__ W, u16* __restrict__ o) {
  const size_t cid = (size_t)blockIdx.x * 256 + threadIdx.x;  // < 4,096,000
  const float4* s4 = (const float4*)(W + cid * 8);
  float4 v0 = s4[0], v1 = s4[1];
  u16x8 r;
  r[0]=f2bf(v0.x); r[1]=f2bf(v0.y); r[2]=f2bf(v0.z); r[3]=f2bf(v0.w);
  r[4]=f2bf(v1.x); r[5]=f2bf(v1.y); r[6]=f2bf(v1.z); r[7]=f2bf(v1.w);
  *(u16x8*)(o + cid * 8) = r;
}

// X[t] frag-packed
__global__ void pack_x(const float* __restrict__ emb, const int* __restrict__ tgt,
                       u16* __restrict__ X) {
  const int cid = blockIdx.x * 256 + threadIdx.x;    // < 524,288
  const int kc = cid & 127, b = (cid >> 7) & 63, t = cid >> 13;
  const int tok = (t == 0) ? kEOS : tgt[b * 64 + t - 1];
  const float4* s4 = (const float4*)(emb + (size_t)tok * 1024 + kc * 8);
  float4 v0 = s4[0], v1 = s4[1];
  u16x8 r;
  r[0]=f2bf(v0.x); r[1]=f2bf(v0.y); r[2]=f2bf(v0.z); r[3]=f2bf(v0.w);
  r[4]=f2bf(v1.x); r[5]=f2bf(v1.y); r[6]=f2bf(v1.z); r[7]=f2bf(v1.w);
  *(u16x8*)(X + (size_t)t * 65536 + packed_off(b, kc * 8)) = r;
}

// hball[lay][slot 0] = bf16(h0[lay]) frag-packed; bsum
__global__ void pack_init(const float* __restrict__ h0, const float* __restrict__ bih,
                          const float* __restrict__ bhh, u16* __restrict__ hball,
                          float* __restrict__ bsum) {
  const int cid = blockIdx.x * 256 + threadIdx.x;    // grid = 192*256 = 49,152 exact
  if (cid < 32768) {
    const int kc = cid & 127, row = cid >> 7;        // row = lay*64 + b
    const int lay = row >> 6, b = row & 63;
    const float4* s4 = (const float4*)(h0 + (size_t)cid * 8);
    float4 v0 = s4[0], v1 = s4[1];
    u16x8 r;
    r[0]=f2bf(v0.x); r[1]=f2bf(v0.y); r[2]=f2bf(v0.z); r[3]=f2bf(v0.w);
    r[4]=f2bf(v1.x); r[5]=f2bf(v1.y); r[6]=f2bf(v1.z); r[7]=f2bf(v1.w);
    *(u16x8*)(hball + (size_t)lay * 65 * 65536 + packed_off(b, kc * 8)) = r;
  } else {
    const int i = cid - 32768;   // < 16384 = L*4H
    bsum[i] = bih[i] + bhh[i];
  }
}

// ---------------- flag-synced recurrence (no fences, no buffer reuse) ----------------
// 256 blocks x 512 thr (cooperative for co-residency).
// block: lay = blk>>6, 16 hidden units (64 gate cols).
// Wave roles: cmat = w>>2 (0: x@Wi^T, 1: h@Wh^T), cwc = (w>>1)&1 (col half),
//             ckh = w&1 (k-slice parity). B-weights register-resident.
// h storage: hball[lay][slot t+1] (write-once -> consumers' reads are first-touch,
// always fresh from LLC -> no acquire fence / L2 invalidate needed).
// Sync: flags[lay*64+cb].v = t+1 (monotonic, own cache line, agent-scope store after
// vmcnt-draining __syncthreads); consumers spin per-thread on 128 distinct lines.
__global__ void __launch_bounds__(512)
lstm_coop(const u16* __restrict__ wpack, const u16* __restrict__ xall,
          u16* __restrict__ hball, const float* __restrict__ bsum,
          const float* __restrict__ c0, float* __restrict__ outh, float* __restrict__ outc,
          Flag* flags) {
  __shared__ u16 stg[3][32][512];    // [buf][mat*16 + mtile*4 + ksl][lane*8]  = 96 KB
  __shared__ float Gc[2][64][68];    // partial gates by cmat; padded          = 34.8 KB

  const int tid = threadIdx.x, lane = tid & 63, wave = tid >> 6;
  const int l15 = lane & 15, l4 = lane >> 4;
  const int cmat = wave >> 2, cwc = (wave >> 1) & 1, ckh = wave & 1;
  const int blk = blockIdx.x, lay = blk >> 6, cb = blk & 63, u0 = cb << 4;
  const int ub = tid >> 3, uu = (tid & 7) * 2;

  float creg0 = c0[((size_t)lay * 64 + ub) * 1024 + u0 + uu];
  float creg1 = c0[((size_t)lay * 64 + ub) * 1024 + u0 + uu + 1];
  float bsv[8];
  #pragma unroll
  for (int g = 0; g < 4; ++g) {
    bsv[g]     = bsum[lay * 4096 + g * 1024 + u0 + uu];
    bsv[4 + g] = bsum[lay * 4096 + g * 1024 + u0 + uu + 1];
  }

  // weights -> registers: 2 col-frags x 16 k-slice pairs (parity ckh).
  // breg[ci][j] holds global k-slice kk = 2*j + ckh.
  const size_t wbase = (size_t)blk * 131072;
  bf16x8 breg[2][16];
  #pragma unroll
  for (int ci = 0; ci < 2; ++ci)
    #pragma unroll
    for (int j = 0; j < 16; ++j)
      breg[ci][j] = *(const bf16x8*)(wpack + wbase
          + (size_t)(((cmat * 32 + 2 * j + ckh) * 4) + cwc * 2 + ci) * 512 + lane * 8);

  u16* hlay = hball + (size_t)lay * 65 * 65536;               // this layer's 65 slots
  const u16* hprev = (lay == 0) ? xall : (hball + (size_t)(lay - 1) * 65 * 65536);

  #pragma unroll 1
  for (int t = 0; t < kT; ++t) {
    // --- dependency waits: 128 spinners on 128 distinct flag lines, one barrier ---
    if (t > 0 && tid < 64)               spin_ge(&flags[lay * 64 + tid].v, t);
    if (lay > 0 && tid >= 64 && tid < 128) spin_ge(&flags[(lay - 1) * 64 + (tid - 64)].v, t + 1);
    __syncthreads();

    const u16* xsrc = (lay == 0) ? (xall + (size_t)t * 65536)
                                 : (hprev + (size_t)(t + 1) * 65536);
    const u16* hsrc = hlay + (size_t)t * 65536;   // h(t-1): slot t (slot 0 = h0)

    auto STAGE = [&](int c) {   // stage k-chunk c (32 KB): 8 waves x 4 linear 1KB tiles
      #pragma unroll
      for (int q = 0; q < 4; ++q) {
        const int j = wave * 4 + q;
        const int m2 = j >> 4, mt = (j >> 2) & 3, ksl = j & 3;   // global ks = c*4 + ksl
        const u16* g = (m2 ? hsrc : xsrc) + (size_t)((mt * 32 + c * 4 + ksl) * 512) + lane * 8;
        async16(g, &stg[c % 3][m2 * 16 + mt * 4 + ksl][0]);
      }
    };

    f32x4 acc[4][2] = {};
    STAGE(0); STAGE(1);
    #pragma unroll
    for (int c = 0; c < 8; ++c) {
      if (c < 7) asm volatile("s_waitcnt vmcnt(4)" ::: "memory");
      else       asm volatile("s_waitcnt vmcnt(0)" ::: "memory");
      __builtin_amdgcn_s_barrier();
      asm volatile("" ::: "memory");
      if (c < 6) STAGE(c + 2);
      const u16* As = &stg[c % 3][cmat * 16][0];
      #pragma unroll
      for (int s = 0; s < 2; ++s) {
        const int ksl = 2 * s + ckh;            // global ks = 4c + 2s + ckh = 2*(2c+s)+ckh
        bf16x8 a[4];
        #pragma unroll
        for (int m = 0; m < 4; ++m)
          a[m] = *(const bf16x8*)(As + (m * 4 + ksl) * 512 + lane * 8);
        #pragma unroll
        for (int m = 0; m < 4; ++m) {
          acc[m][0] = __builtin_amdgcn_mfma_f32_16x16x32_bf16(a[m], breg[0][2 * c + s], acc[m][0], 0, 0, 0);
          acc[m][1] = __builtin_amdgcn_mfma_f32_16x16x32_bf16(a[m], breg[1][2 * c + s], acc[m][1], 0, 0, 0);
        }
      }
    }

    // --- two-phase partial-gate reduction into Gc[cmat] ---
    if (ckh == 0) {
      #pragma unroll
      for (int m = 0; m < 4; ++m)
        #pragma unroll
        for (int ci = 0; ci < 2; ++ci)
          #pragma unroll
          for (int r = 0; r < 4; ++r)
            Gc[cmat][m * 16 + l4 * 4 + r][cwc * 32 + ci * 16 + l15] = acc[m][ci][r];
    }
    __syncthreads();
    if (ckh == 1) {
      #pragma unroll
      for (int m = 0; m < 4; ++m)
        #pragma unroll
        for (int ci = 0; ci < 2; ++ci)
          #pragma unroll
          for (int r = 0; r < 4; ++r)
            Gc[cmat][m * 16 + l4 * 4 + r][cwc * 32 + ci * 16 + l15] += acc[m][ci][r];
    }
    __syncthreads();

    // --- cell update: thread = (batch ub, units uu,uu+1) ---
    float2 sg[4];
    #pragma unroll
    for (int g = 0; g < 4; ++g) {
      const int col = g * 16 + uu;
      const float2 v0 = *(const float2*)&Gc[0][ub][col];
      const float2 v1 = *(const float2*)&Gc[1][ub][col];
      sg[g] = make_float2(v0.x + v1.x, v0.y + v1.y);
    }
    u16 hv[2];
    #pragma unroll
    for (int p = 0; p < 2; ++p) {
      const float gi = (p ? sg[0].y : sg[0].x) + bsv[p * 4 + 0];
      const float gf = (p ? sg[1].y : sg[1].x) + bsv[p * 4 + 1];
      const float gg = (p ? sg[2].y : sg[2].x) + bsv[p * 4 + 2];
      const float go = (p ? sg[3].y : sg[3].x) + bsv[p * 4 + 3];
      const float cr = (p == 0) ? creg0 : creg1;
      const float c2 = sigf(gf) * cr + sigf(gi) * tanhf_(gg);
      const float h2 = sigf(go) * tanhf_(c2);
      if (p == 0) creg0 = c2; else creg1 = c2;
      hv[p] = f2bf(h2);
      if (t == kT - 1) {
        outh[((size_t)lay * 64 + ub) * 1024 + u0 + uu + p] = h2;
        outc[((size_t)lay * 64 + ub) * 1024 + u0 + uu + p] = c2;
      }
    }
    // publish h(t) to slot t+1 (write-once), agent-scope (coherent at LLC on retire)
    const u32 hpair = (u32)hv[0] | ((u32)hv[1] << 16);
    u32* hdst = (u32*)(hlay + (size_t)(t + 1) * 65536 + packed_off(ub, u0 + uu));
    __hip_atomic_store(hdst, hpair, __ATOMIC_RELAXED, __HIP_MEMORY_SCOPE_AGENT);

    // __syncthreads drains each wave's vmcnt: all h stores coherent before flag
    __syncthreads();
    if (tid == 0)
      __hip_atomic_store(&flags[lay * 64 + cb].v, t + 1, __ATOMIC_RELAXED, __HIP_MEMORY_SCOPE_AGENT);
  }
}

// ---------------- classifier GEMM (full path): A = hball[3][1..64], Bw pre-packed bf16 ----------------
__global__ void __launch_bounds__(256)
cls_gemm(const u16* __restrict__ A, const u16* __restrict__ Bw,
         const float* __restrict__ bcls, float* __restrict__ out) {
  __shared__ u16 sA[2][4096], sB[2][4096];
  const int tid = threadIdx.x, lane = tid & 63, wave = tid >> 6;
  const int wm = wave >> 1, wc = wave & 1;
  const int l15 = lane & 15, l4 = lane >> 4;
  const int bn = blockIdx.x, bm = blockIdx.y;
  const u16* Ab = A  + (size_t)bm * 131072;   // two packed 64x1024 t-matrices
  const u16* Bb = Bw + (size_t)bn * 131072;

  auto STAGE = [&](int kk) {
    u16* dA = sA[kk & 1]; u16* dB = sB[kk & 1];
    #pragma unroll
    for (int q = 0; q < 4; ++q) {
      const int u = wave * 4 + q;
      if (u < 8) {  // A: tiles [tq=u>>2][mtile=u&3] at k-slice kk (packed, linear)
        const u16* g = Ab + (size_t)(u >> 2) * 65536 + (size_t)(((u & 3) * 32 + kk) * 512) + lane * 8;
        async16(g, dA + u * 512);
      } else {      // B: row-major staging
        const int v = u & 7;
        const u16* g = Bb + (size_t)((v & 1) * 64 + lane) * 1024 + kk * 32 + (v >> 1) * 8;
        async16(g, dB + v * 512);
      }
    }
  };

  f32x4 acc[4][4] = {};
  STAGE(0);
  for (int kk = 0; kk < 32; ++kk) {
    if (kk < 31) { STAGE(kk + 1); asm volatile("s_waitcnt vmcnt(4)" ::: "memory"); }
    else         asm volatile("s_waitcnt vmcnt(0)" ::: "memory");
    __builtin_amdgcn_s_barrier();
    asm volatile("" ::: "memory");
    const u16* aS = sA[kk & 1]; const u16* bS = sB[kk & 1];
    bf16x8 av[4], bv[4];
    #pragma unroll
    for (int mi = 0; mi < 4; ++mi) av[mi] = *(const bf16x8*)(aS + (wm * 4 + mi) * 512 + lane * 8);
    #pragma unroll
    for (int ci = 0; ci < 4; ++ci) bv[ci] = *(const bf16x8*)(bS + l4 * 1024 + (wc * 64 + ci * 16 + l15) * 8);
    #pragma unroll
    for (int mi = 0; mi < 4; ++mi)
      #pragma unroll
      for (int ci = 0; ci < 4; ++ci)
        acc[mi][ci] = __builtin_amdgcn_mfma_f32_16x16x32_bf16(av[mi], bv[ci], acc[mi][ci], 0, 0, 0);
    asm volatile("" ::: "memory");
    __builtin_amdgcn_s_barrier();
  }
  #pragma unroll
  for (int ci = 0; ci < 4; ++ci) {
    const int col = bn * 128 + wc * 64 + ci * 16 + l15;
    const float bc = bcls[col];
    #pragma unroll
    for (int mi = 0; mi < 4; ++mi) {
      #pragma unroll
      for (int r = 0; r < 4; ++r) {
        const int row = bm * 128 + wm * 64 + mi * 16 + l4 * 4 + r;
        out[(size_t)row * 32000 + col] = acc[mi][ci][r] + bc;
      }
    }
  }
}

// ---------------- classifier GEMM (compact path): Bw f32 converted on the fly ----------------
__global__ void __launch_bounds__(256)
cls_gemm_f32(const u16* __restrict__ A, const float* __restrict__ Bw,
             const float* __restrict__ bcls, float* __restrict__ out) {
  __shared__ u16 sA[2][4096], sB[2][4096];
  const int tid = threadIdx.x, lane = tid & 63, wave = tid >> 6;
  const int wm = wave >> 1, wc = wave & 1;
  const int l15 = lane & 15, l4 = lane >> 4;
  const int bn = blockIdx.x, bm = blockIdx.y;
  const u16*  Ab = A  + (size_t)bm * 131072;
  const float* Bb = Bw + (size_t)bn * 131072;

  auto LOADB = [&](int kk, u16x8* rb) {
    #pragma unroll
    for (int q = 0; q < 2; ++q) {
      const int p = tid + q * 256, row = p & 127, khi = p >> 7;
      const float4* s4 = (const float4*)(Bb + (size_t)row * 1024 + kk * 32 + khi * 8);
      float4 v0 = s4[0], v1 = s4[1];
      u16x8 r;
      r[0]=f2bf(v0.x); r[1]=f2bf(v0.y); r[2]=f2bf(v0.z); r[3]=f2bf(v0.w);
      r[4]=f2bf(v1.x); r[5]=f2bf(v1.y); r[6]=f2bf(v1.z); r[7]=f2bf(v1.w);
      rb[q] = r;
    }
  };
  auto WRITEB = [&](int kk, const u16x8* rb) {
    u16* dB = sB[kk & 1];
    #pragma unroll
    for (int q = 0; q < 2; ++q) {
      const int p = tid + q * 256;
      *(u16x8*)(dB + p * 8) = rb[q];
    }
  };
  auto STAGE_A = [&](int kk) {
    u16* dA = sA[kk & 1];
    #pragma unroll
    for (int q = 0; q < 2; ++q) {
      const int v = wave * 2 + q;
      const u16* g = Ab + (size_t)(v >> 2) * 65536 + (size_t)(((v & 3) * 32 + kk) * 512) + lane * 8;
      async16(g, dA + v * 512);
    }
  };

  f32x4 acc[4][4] = {};
  {
    u16x8 rb[2];
    LOADB(0, rb); STAGE_A(0); WRITEB(0, rb);
  }
  for (int kk = 0; kk < 32; ++kk) {
    if (kk < 31) {
      u16x8 rb[2];
      LOADB(kk + 1, rb);
      STAGE_A(kk + 1);
      WRITEB(kk + 1, rb);
    } else {
      asm volatile("s_waitcnt vmcnt(0)" ::: "memory");
    }
    __builtin_amdgcn_s_barrier();
    asm volatile("" ::: "memory");
    const u16* aS = sA[kk & 1]; const u16* bS = sB[kk & 1];
    bf16x8 av[4], bv[4];
    #pragma unroll
    for (int mi = 0; mi < 4; ++mi) av[mi] = *(const bf16x8*)(aS + (wm * 4 + mi) * 512 + lane * 8);
    #pragma unroll
    for (int ci = 0; ci < 4; ++ci) bv[ci] = *(const bf16x8*)(bS + l4 * 1024 + (wc * 64 + ci * 16 + l15) * 8);
    #pragma unroll
    for (int mi = 0; mi < 4; ++mi)
      #pragma unroll
      for (int ci = 0; ci < 4; ++ci)
        acc[mi][ci] = __builtin_amdgcn_mfma_f32_16x16x32_bf16(av[mi], bv[ci], acc[mi][ci], 0, 0, 0);
    asm volatile("" ::: "memory");
    __builtin_amdgcn_s_barrier();
  }
  #pragma unroll
  for (int ci = 0; ci < 4; ++ci) {
    const int col = bn * 128 + wc * 64 + ci * 16 + l15;
    const float bc = bcls[col];
    #pragma unroll
    for (int mi = 0; mi < 4; ++mi) {
      #pragma unroll
      for (int r = 0; r < 4; ++r) {
        const int row = bm * 128 + wm * 64 + mi * 16 + l4 * 4 + r;
        out[(size_t)row * 32000 + col] = acc[mi][ci][r] + bc;
      }
    }
  }
}

// ---------------- fused log-softmax ----------------
__global__ void __launch_bounds__(256)
lsm_k(float* __restrict__ out) {
  __shared__ float red[256];
  const int r = blockIdx.x;
  float* p = out + (size_t)r * 32000;
  const float4* p4 = (const float4*)p;
  float m = -3.0e38f;
  for (int v = threadIdx.x; v < 8000; v += 256) {
    const float4 x = p4[v];
    m = fmaxf(m, fmaxf(fmaxf(x.x, x.y), fmaxf(x.z, x.w)));
  }
  red[threadIdx.x] = m; __syncthreads();
  for (int s2 = 128; s2 > 0; s2 >>= 1) {
    if ((int)threadIdx.x < s2) red[threadIdx.x] = fmaxf(red[threadIdx.x], red[threadIdx.x + s2]);
    __syncthreads();
  }
  m = red[0]; __syncthreads();
  float s = 0.0f;
  for (int v = threadIdx.x; v < 8000; v += 256) {
    const float4 x = p4[v];
    s += __expf(x.x - m) + __expf(x.y - m) + __expf(x.z - m) + __expf(x.w - m);
  }
  red[threadIdx.x] = s; __syncthreads();
  for (int s2 = 128; s2 > 0; s2 >>= 1) {
    if ((int)threadIdx.x < s2) red[threadIdx.x] += red[threadIdx.x + s2];
    __syncthreads();
  }
  const float z = m + logf(red[0]);
  float4* q4 = (float4*)p;
  for (int v = threadIdx.x; v < 8000; v += 256) {
    float4 x = p4[v];
    x.x -= z; x.y -= z; x.z -= z; x.w -= z;
    q4[v] = x;
  }
}

// ---------------- host ----------------
extern "C" void kernel_launch(void* const* d_in, const int* in_sizes, int n_in,
                              void* d_out, int out_size, void* d_ws, size_t ws_size,
                              hipStream_t stream) {
  (void)in_sizes; (void)n_in; (void)out_size;
  const int*   tgt  = (const int*)d_in[1];
  const float* h0   = (const float*)d_in[2];
  const float* c0   = (const float*)d_in[3];
  const float* emb  = (const float*)d_in[4];
  const float* Wih  = (const float*)d_in[5];
  const float* Whh  = (const float*)d_in[6];
  const float* bih  = (const float*)d_in[7];
  const float* bhh  = (const float*)d_in[8];
  const float* Wcls = (const float*)d_in[9];
  const float* bcls = (const float*)d_in[10];

  float* out  = (float*)d_out;
  float* outh = out + (size_t)kT * kB * kV;          // 131,072,000
  float* outc = outh + (size_t)kL * kB * kH;         // +262,144

  const size_t SZ_WPACK = 67108864;   // L*2*4H*H bf16
  const size_t SZ_WCLS  = 65536000;   // V*H bf16
  const size_t SZ_X     = 8388608;    // T*B*H bf16 (frag-packed)
  const size_t SZ_HBALL = 34078720;   // L*65*B*H bf16 (frag-packed, write-once slots)
  const size_t SZ_BSUM  = 65536;      // L*4H f32
  const size_t SZ_FLAGS = 16384;      // 256 * 64B
  const size_t FULL_REQ = SZ_WPACK + SZ_WCLS + SZ_X + SZ_HBALL + SZ_BSUM + SZ_FLAGS;
  const bool full = (ws_size >= FULL_REQ);

  char* ws = (char*)d_ws;
  size_t off = 0;
  u16* wpack = (u16*)(ws + off); off += SZ_WPACK;
  u16* wclsb = nullptr;
  if (full) { wclsb = (u16*)(ws + off); off += SZ_WCLS; }
  u16*   X     = (u16*)(ws + off); off += SZ_X;
  u16*   hball = (u16*)(ws + off); off += SZ_HBALL;
  float* bsum  = (float*)(ws + off); off += SZ_BSUM;
  Flag*  flags = (Flag*)(ws + off);  off += SZ_FLAGS;

  pack_lstm<<<16384, 256, 0, stream>>>(Wih, Whh, wpack);
  if (full) pack_cls<<<16000, 256, 0, stream>>>(Wcls, wclsb);
  pack_x   <<<2048,  256, 0, stream>>>(emb, tgt, X);
  pack_init<<<192,   256, 0, stream>>>(h0, bih, bhh, hball, bsum);
  hipMemsetAsync(flags, 0, SZ_FLAGS, stream);

  void* args[] = { (void*)&wpack, (void*)&X, (void*)&hball, (void*)&bsum,
                   (void*)&c0, (void*)&outh, (void*)&outc, (void*)&flags };
  hipLaunchCooperativeKernel((const void*)lstm_coop, dim3(256), dim3(512), args, 0, stream);

  // classifier input A = hball[3][slots 1..64] (64 contiguous packed 64x1024 matrices)
  const u16* h3a = hball + (size_t)3 * 65 * 65536 + 65536;
  if (full) cls_gemm    <<<dim3(250, 32), 256, 0, stream>>>(h3a, wclsb, bcls, out);
  else      cls_gemm_f32<<<dim3(250, 32), 256, 0, stream>>>(h3a, Wcls,  bcls, out);
  lsm_k<<<4096, 256, 0, stream>>>(out);
}

// Round 7
// 1413.714 us; speedup vs baseline: 4.6936x; 1.0260x over previous
//
#include <hip/hip_runtime.h>

using u16 = unsigned short;
using u32 = unsigned int;

typedef __bf16 bf16x8 __attribute__((ext_vector_type(8)));
typedef float  f32x4  __attribute__((ext_vector_type(4)));
typedef u16    u16x8  __attribute__((ext_vector_type(8)));

static constexpr int kV = 32000, kH = 1024, kB = 64, kT = 64, kL = 4, kEOS = 2;

struct Flag { int v; int pad[15]; };   // one 64B line per flag

__device__ __forceinline__ u16 f2bf(float f) {
  u32 u = __float_as_uint(f);
  u = (u + 0x7fffu + ((u >> 16) & 1u)) >> 16;
  return (u16)u;
}
__device__ __forceinline__ float sigf(float x)   { return 1.0f / (1.0f + __expf(-x)); }
__device__ __forceinline__ float tanhf_(float x) { return 1.0f - 2.0f / (__expf(2.0f * x) + 1.0f); }

typedef const __attribute__((address_space(1))) u32* gas_ptr;
typedef __attribute__((address_space(3))) u32*       las_ptr;
__device__ __forceinline__ void async16(const u16* g, u16* l) {
  __builtin_amdgcn_global_load_lds((gas_ptr)g, (las_ptr)l, 16, 0, 0);
}

__device__ __forceinline__ void spin_ge(const int* p, int tgt) {
  while (__hip_atomic_load(p, __ATOMIC_RELAXED, __HIP_MEMORY_SCOPE_AGENT) < tgt)
    __builtin_amdgcn_s_sleep(2);
}

// Frag-packed 64x1024 bf16 matrix: [mtile=b>>4][ks=k>>5][lane=((k>>3)&3)*16+(b&15)][elem=k&7]
__device__ __forceinline__ size_t packed_off(int b, int k) {
  return (size_t)(((b >> 4) * 32 + (k >> 5)) * 512 + (((k >> 3) & 3) * 16 + (b & 15)) * 8 + (k & 7));
}

// ---------------- prep kernels ----------------

// wpack[blk(256)][mat(2)][kk(32)][cf(4)][lane(64)][8]
__global__ void pack_lstm(const float* __restrict__ Wih, const float* __restrict__ Whh,
                          u16* __restrict__ wpack) {
  const int cid  = blockIdx.x * 256 + threadIdx.x;   // < 4,194,304
  const int lane = cid & 63;
  const int cf   = (cid >> 6) & 3;
  const int kk   = (cid >> 8) & 31;
  const int mt   = (cid >> 13) & 1;
  const int blk  = cid >> 14;
  const int lay = blk >> 6, cb = blk & 63;
  const int wr = cf * 1024 + cb * 16 + (lane & 15);
  const int kb = kk * 32 + (lane >> 4) * 8;
  const float* src = (mt ? Whh : Wih) + ((size_t)lay * 4096 + wr) * 1024 + kb;
  const float4* s4 = (const float4*)src;
  float4 v0 = s4[0], v1 = s4[1];
  u16x8 r;
  r[0]=f2bf(v0.x); r[1]=f2bf(v0.y); r[2]=f2bf(v0.z); r[3]=f2bf(v0.w);
  r[4]=f2bf(v1.x); r[5]=f2bf(v1.y); r[6]=f2bf(v1.z); r[7]=f2bf(v1.w);
  *(u16x8*)(wpack + (size_t)cid * 8) = r;
}

__global__ void pack_cls(const float* __restrict__ W, u16* __restrict__ o) {
  const size_t cid = (size_t)blockIdx.x * 256 + threadIdx.x;  // < 4,096,000
  const float4* s4 = (const float4*)(W + cid * 8);
  float4 v0 = s4[0], v1 = s4[1];
  u16x8 r;
  r[0]=f2bf(v0.x); r[1]=f2bf(v0.y); r[2]=f2bf(v0.z); r[3]=f2bf(v0.w);
  r[4]=f2bf(v1.x); r[5]=f2bf(v1.y); r[6]=f2bf(v1.z); r[7]=f2bf(v1.w);
  *(u16x8*)(o + cid * 8) = r;
}

__global__ void pack_x(const float* __restrict__ emb, const int* __restrict__ tgt,
                       u16* __restrict__ X) {
  const int cid = blockIdx.x * 256 + threadIdx.x;    // < 524,288
  const int kc = cid & 127, b = (cid >> 7) & 63, t = cid >> 13;
  const int tok = (t == 0) ? kEOS : tgt[b * 64 + t - 1];
  const float4* s4 = (const float4*)(emb + (size_t)tok * 1024 + kc * 8);
  float4 v0 = s4[0], v1 = s4[1];
  u16x8 r;
  r[0]=f2bf(v0.x); r[1]=f2bf(v0.y); r[2]=f2bf(v0.z); r[3]=f2bf(v0.w);
  r[4]=f2bf(v1.x); r[5]=f2bf(v1.y); r[6]=f2bf(v1.z); r[7]=f2bf(v1.w);
  *(u16x8*)(X + (size_t)t * 65536 + packed_off(b, kc * 8)) = r;
}

__global__ void pack_init(const float* __restrict__ h0, const float* __restrict__ bih,
                          const float* __restrict__ bhh, u16* __restrict__ hball,
                          float* __restrict__ bsum) {
  const int cid = blockIdx.x * 256 + threadIdx.x;    // grid = 192*256
  if (cid < 32768) {
    const int kc = cid & 127, row = cid >> 7;        // row = lay*64 + b
    const int lay = row >> 6, b = row & 63;
    const float4* s4 = (const float4*)(h0 + (size_t)cid * 8);
    float4 v0 = s4[0], v1 = s4[1];
    u16x8 r;
    r[0]=f2bf(v0.x); r[1]=f2bf(v0.y); r[2]=f2bf(v0.z); r[3]=f2bf(v0.w);
    r[4]=f2bf(v1.x); r[5]=f2bf(v1.y); r[6]=f2bf(v1.z); r[7]=f2bf(v1.w);
    *(u16x8*)(hball + (size_t)lay * 65 * 65536 + packed_off(b, kc * 8)) = r;
  } else {
    const int i = cid - 32768;   // < 16384
    bsum[i] = bih[i] + bhh[i];
  }
}

// ---------------- recurrence: 256 blocks x 1024 thr (16 waves, 4/SIMD) ----------------
// Wave role: cmat = w>>3 (0: x@Wi^T, 1: h@Wh^T), cwc = (w>>1)&3 (16-col frag = gate),
//            ckh = w&1 (k-slice parity). breg[16] = 64 VGPRs/wave, register-resident.
// K in 8 chunks of 128; ring-2 LDS; schedule: vmcnt(0) -> barrier -> STAGE(c+1) -> compute(c).
__global__ void __launch_bounds__(1024, 4)
lstm_coop(const u16* __restrict__ wpack, const u16* __restrict__ xall,
          u16* __restrict__ hball, const float* __restrict__ bsum,
          const float* __restrict__ c0, float* __restrict__ outh, float* __restrict__ outc,
          Flag* flags) {
  __shared__ u16 stg[2][32][512];    // 64 KB: [buf][mat*16 + mtile*4 + ksl][lane*8]
  __shared__ float Gc[4][64][66];    // 67.6 KB: 4 partials (q = cmat*2+ckh), rows=batch, cols=gatecol

  const int tid = threadIdx.x, lane = tid & 63, wave = tid >> 6;
  const int l15 = lane & 15, l4 = lane >> 4;
  const int cmat = wave >> 3, cwc = (wave >> 1) & 3, ckh = wave & 1;
  const int blk = blockIdx.x, lay = blk >> 6, cb = blk & 63, u0 = cb << 4;
  const int ub = tid >> 4, uu = tid & 15;       // update: 1 batch row, 1 unit per thread

  float creg = c0[((size_t)lay * 64 + ub) * 1024 + u0 + uu];
  float bsv[4];
  #pragma unroll
  for (int g = 0; g < 4; ++g) bsv[g] = bsum[lay * 4096 + g * 1024 + u0 + uu];

  // weights -> registers: breg[j] = k-slice kk = 2*j + ckh, col-frag cwc, matrix cmat
  const size_t wbase = (size_t)blk * 131072;
  bf16x8 breg[16];
  #pragma unroll
  for (int j = 0; j < 16; ++j)
    breg[j] = *(const bf16x8*)(wpack + wbase
        + (size_t)(((cmat * 32 + 2 * j + ckh) * 4) + cwc) * 512 + lane * 8);

  // staging role: this wave stages tiles j = wave*2 + {0,1}
  const int j0 = wave * 2, j1 = wave * 2 + 1;
  const int m2a = j0 >> 4, mta = (j0 >> 2) & 3, ksla = j0 & 3;
  const int m2b = j1 >> 4, mtb = (j1 >> 2) & 3, kslb = j1 & 3;

  u16* hlay = hball + (size_t)lay * 65 * 65536;
  const u16* hprev = (lay == 0) ? xall : (hball + (size_t)(lay - 1) * 65 * 65536);

  #pragma unroll 1
  for (int t = 0; t < kT; ++t) {
    // --- dependency waits: 128 spinners on distinct flag lines ---
    if (t > 0 && tid < 64)                 spin_ge(&flags[lay * 64 + tid].v, t);
    if (lay > 0 && tid >= 64 && tid < 128) spin_ge(&flags[(lay - 1) * 64 + (tid - 64)].v, t + 1);
    __syncthreads();

    const u16* xsrc = (lay == 0) ? (xall + (size_t)t * 65536)
                                 : (hprev + (size_t)(t + 1) * 65536);
    const u16* hsrc = hlay + (size_t)t * 65536;   // h(t-1) = slot t

    const u16* ga = (m2a ? hsrc : xsrc) + (size_t)((mta * 32 + ksla) * 512) + lane * 8;
    const u16* gb = (m2b ? hsrc : xsrc) + (size_t)((mtb * 32 + kslb) * 512) + lane * 8;
    u16* da = &stg[0][m2a * 16 + mta * 4 + ksla][0];
    u16* db = &stg[0][m2b * 16 + mtb * 4 + kslb][0];

    auto STAGE = [&](int c) {   // chunk c: +c*4 k-slices = +c*2048 u16
      async16(ga + (size_t)c * 2048, da + (c & 1) * 16384);
      async16(gb + (size_t)c * 2048, db + (c & 1) * 16384);
    };

    f32x4 acc[4] = {};
    STAGE(0);
    #pragma unroll
    for (int c = 0; c < 8; ++c) {
      asm volatile("s_waitcnt vmcnt(0)" ::: "memory");
      __builtin_amdgcn_s_barrier();
      asm volatile("" ::: "memory");
      if (c < 7) STAGE(c + 1);
      const u16* As = &stg[c & 1][cmat * 16][0];
      #pragma unroll
      for (int s = 0; s < 2; ++s) {
        const int ksl = 2 * s + ckh;
        bf16x8 a[4];
        #pragma unroll
        for (int m = 0; m < 4; ++m)
          a[m] = *(const bf16x8*)(As + (m * 4 + ksl) * 512 + lane * 8);
        #pragma unroll
        for (int m = 0; m < 4; ++m)
          acc[m] = __builtin_amdgcn_mfma_f32_16x16x32_bf16(a[m], breg[2 * c + s], acc[m], 0, 0, 0);
      }
    }

    // --- single-phase partial write (4 q-copies), one barrier ---
    {
      const int q = cmat * 2 + ckh;
      #pragma unroll
      for (int m = 0; m < 4; ++m)
        #pragma unroll
        for (int r = 0; r < 4; ++r)
          Gc[q][m * 16 + l4 * 4 + r][cwc * 16 + l15] = acc[m][r];
    }
    __syncthreads();

    // --- cell update: 1 unit per thread ---
    float sg[4];
    #pragma unroll
    for (int g = 0; g < 4; ++g) {
      const int col = g * 16 + uu;
      sg[g] = Gc[0][ub][col] + Gc[1][ub][col] + Gc[2][ub][col] + Gc[3][ub][col] + bsv[g];
    }
    const float c2 = sigf(sg[1]) * creg + sigf(sg[0]) * tanhf_(sg[2]);
    const float h2 = sigf(sg[3]) * tanhf_(c2);
    creg = c2;
    const u16 hv = f2bf(h2);
    if (t == kT - 1) {
      outh[((size_t)lay * 64 + ub) * 1024 + u0 + uu] = h2;
      outc[((size_t)lay * 64 + ub) * 1024 + u0 + uu] = c2;
    }
    // publish: pair adjacent units into one u32 agent-scope store
    const u32 other = __shfl_xor((u32)hv, 1);
    if ((tid & 1) == 0) {
      const u32 hpair = (u32)hv | (other << 16);
      u32* hdst = (u32*)(hlay + (size_t)(t + 1) * 65536 + packed_off(ub, u0 + uu));
      __hip_atomic_store(hdst, hpair, __ATOMIC_RELAXED, __HIP_MEMORY_SCOPE_AGENT);
    }
    __syncthreads();   // drains vmcnt: h stores coherent before flag
    if (tid == 0)
      __hip_atomic_store(&flags[lay * 64 + cb].v, t + 1, __ATOMIC_RELAXED, __HIP_MEMORY_SCOPE_AGENT);
  }
}

// ---------------- classifier GEMM + fused row-stats epilogue ----------------
#define CLS_EPILOGUE()                                                                     \
  {                                                                                        \
    float* sR = (float*)&sA[0][0];                                                         \
    _Pragma("unroll")                                                                      \
    for (int mi = 0; mi < 4; ++mi) {                                                       \
      _Pragma("unroll")                                                                    \
      for (int r = 0; r < 4; ++r) {                                                        \
        float v[4];                                                                        \
        _Pragma("unroll")                                                                  \
        for (int ci = 0; ci < 4; ++ci) v[ci] = acc[mi][ci][r] + bc[ci];                     \
        float mx = fmaxf(fmaxf(v[0], v[1]), fmaxf(v[2], v[3]));                            \
        mx = fmaxf(mx, __shfl_xor(mx, 1)); mx = fmaxf(mx, __shfl_xor(mx, 2));              \
        mx = fmaxf(mx, __shfl_xor(mx, 4)); mx = fmaxf(mx, __shfl_xor(mx, 8));              \
        float ss = __expf(v[0]-mx) + __expf(v[1]-mx) + __expf(v[2]-mx) + __expf(v[3]-mx);  \
        ss += __shfl_xor(ss, 1); ss += __shfl_xor(ss, 2);                                  \
        ss += __shfl_xor(ss, 4); ss += __shfl_xor(ss, 8);                                  \
        const int lr = wm * 64 + mi * 16 + l4 * 4 + r;                                     \
        if (wc == 0 && l15 == 0) { sR[lr * 2] = mx; sR[lr * 2 + 1] = ss; }                 \
        __syncthreads();                                                                   \
        if (wc == 1 && l15 == 0) {                                                         \
          const float m0 = sR[lr * 2], s0 = sR[lr * 2 + 1];                                \
          const float M = fmaxf(m0, mx);                                                   \
          const float S = s0 * __expf(m0 - M) + ss * __expf(mx - M);                       \
          const int grow = bm * 128 + lr;                                                  \
          pmax[(size_t)grow * 256 + bn] = M;                                               \
          psum[(size_t)grow * 256 + bn] = S;                                               \
        }                                                                                  \
        __syncthreads();                                                                   \
      }                                                                                    \
    }                                                                                      \
  }

__global__ void __launch_bounds__(256)
cls_gemm(const u16* __restrict__ A, const u16* __restrict__ Bw,
         const float* __restrict__ bcls, float* __restrict__ out,
         float* __restrict__ pmax, float* __restrict__ psum) {
  __shared__ u16 sA[2][4096], sB[2][4096];
  const int tid = threadIdx.x, lane = tid & 63, wave = tid >> 6;
  const int wm = wave >> 1, wc = wave & 1;
  const int l15 = lane & 15, l4 = lane >> 4;
  const int bn = blockIdx.x, bm = blockIdx.y;
  const u16* Ab = A  + (size_t)bm * 131072;
  const u16* Bb = Bw + (size_t)bn * 131072;

  auto STAGE = [&](int kk) {
    u16* dA = sA[kk & 1]; u16* dB = sB[kk & 1];
    #pragma unroll
    for (int q = 0; q < 4; ++q) {
      const int u = wave * 4 + q;
      if (u < 8) {
        const u16* g = Ab + (size_t)(u >> 2) * 65536 + (size_t)(((u & 3) * 32 + kk) * 512) + lane * 8;
        async16(g, dA + u * 512);
      } else {
        const int v = u & 7;
        const u16* g = Bb + (size_t)((v & 1) * 64 + lane) * 1024 + kk * 32 + (v >> 1) * 8;
        async16(g, dB + v * 512);
      }
    }
  };

  f32x4 acc[4][4] = {};
  STAGE(0);
  for (int kk = 0; kk < 32; ++kk) {
    if (kk < 31) { STAGE(kk + 1); asm volatile("s_waitcnt vmcnt(4)" ::: "memory"); }
    else         asm volatile("s_waitcnt vmcnt(0)" ::: "memory");
    __builtin_amdgcn_s_barrier();
    asm volatile("" ::: "memory");
    const u16* aS = sA[kk & 1]; const u16* bS = sB[kk & 1];
    bf16x8 av[4], bv[4];
    #pragma unroll
    for (int mi = 0; mi < 4; ++mi) av[mi] = *(const bf16x8*)(aS + (wm * 4 + mi) * 512 + lane * 8);
    #pragma unroll
    for (int ci = 0; ci < 4; ++ci) bv[ci] = *(const bf16x8*)(bS + l4 * 1024 + (wc * 64 + ci * 16 + l15) * 8);
    #pragma unroll
    for (int mi = 0; mi < 4; ++mi)
      #pragma unroll
      for (int ci = 0; ci < 4; ++ci)
        acc[mi][ci] = __builtin_amdgcn_mfma_f32_16x16x32_bf16(av[mi], bv[ci], acc[mi][ci], 0, 0, 0);
    asm volatile("" ::: "memory");
    __builtin_amdgcn_s_barrier();
  }
  float bc[4];
  #pragma unroll
  for (int ci = 0; ci < 4; ++ci) bc[ci] = bcls[bn * 128 + wc * 64 + ci * 16 + l15];
  #pragma unroll
  for (int ci = 0; ci < 4; ++ci) {
    const int col = bn * 128 + wc * 64 + ci * 16 + l15;
    #pragma unroll
    for (int mi = 0; mi < 4; ++mi)
      #pragma unroll
      for (int r = 0; r < 4; ++r) {
        const int row = bm * 128 + wm * 64 + mi * 16 + l4 * 4 + r;
        out[(size_t)row * 32000 + col] = acc[mi][ci][r] + bc[ci];
      }
  }
  __syncthreads();
  CLS_EPILOGUE()
}

__global__ void __launch_bounds__(256)
cls_gemm_f32(const u16* __restrict__ A, const float* __restrict__ Bw,
             const float* __restrict__ bcls, float* __restrict__ out,
             float* __restrict__ pmax, float* __restrict__ psum) {
  __shared__ u16 sA[2][4096], sB[2][4096];
  const int tid = threadIdx.x, lane = tid & 63, wave = tid >> 6;
  const int wm = wave >> 1, wc = wave & 1;
  const int l15 = lane & 15, l4 = lane >> 4;
  const int bn = blockIdx.x, bm = blockIdx.y;
  const u16*  Ab = A  + (size_t)bm * 131072;
  const float* Bb = Bw + (size_t)bn * 131072;

  auto LOADB = [&](int kk, u16x8* rb) {
    #pragma unroll
    for (int q = 0; q < 2; ++q) {
      const int p = tid + q * 256, row = p & 127, khi = p >> 7;
      const float4* s4 = (const float4*)(Bb + (size_t)row * 1024 + kk * 32 + khi * 8);
      float4 v0 = s4[0], v1 = s4[1];
      u16x8 r;
      r[0]=f2bf(v0.x); r[1]=f2bf(v0.y); r[2]=f2bf(v0.z); r[3]=f2bf(v0.w);
      r[4]=f2bf(v1.x); r[5]=f2bf(v1.y); r[6]=f2bf(v1.z); r[7]=f2bf(v1.w);
      rb[q] = r;
    }
  };
  auto WRITEB = [&](int kk, const u16x8* rb) {
    u16* dB = sB[kk & 1];
    #pragma unroll
    for (int q = 0; q < 2; ++q) *(u16x8*)(dB + (tid + q * 256) * 8) = rb[q];
  };
  auto STAGE_A = [&](int kk) {
    u16* dA = sA[kk & 1];
    #pragma unroll
    for (int q = 0; q < 2; ++q) {
      const int v = wave * 2 + q;
      const u16* g = Ab + (size_t)(v >> 2) * 65536 + (size_t)(((v & 3) * 32 + kk) * 512) + lane * 8;
      async16(g, dA + v * 512);
    }
  };

  f32x4 acc[4][4] = {};
  {
    u16x8 rb[2];
    LOADB(0, rb); STAGE_A(0); WRITEB(0, rb);
  }
  for (int kk = 0; kk < 32; ++kk) {
    if (kk < 31) {
      u16x8 rb[2];
      LOADB(kk + 1, rb);
      STAGE_A(kk + 1);
      WRITEB(kk + 1, rb);
    } else {
      asm volatile("s_waitcnt vmcnt(0)" ::: "memory");
    }
    __builtin_amdgcn_s_barrier();
    asm volatile("" ::: "memory");
    const u16* aS = sA[kk & 1]; const u16* bS = sB[kk & 1];
    bf16x8 av[4], bv[4];
    #pragma unroll
    for (int mi = 0; mi < 4; ++mi) av[mi] = *(const bf16x8*)(aS + (wm * 4 + mi) * 512 + lane * 8);
    #pragma unroll
    for (int ci = 0; ci < 4; ++ci) bv[ci] = *(const bf16x8*)(bS + l4 * 1024 + (wc * 64 + ci * 16 + l15) * 8);
    #pragma unroll
    for (int mi = 0; mi < 4; ++mi)
      #pragma unroll
      for (int ci = 0; ci < 4; ++ci)
        acc[mi][ci] = __builtin_amdgcn_mfma_f32_16x16x32_bf16(av[mi], bv[ci], acc[mi][ci], 0, 0, 0);
    asm volatile("" ::: "memory");
    __builtin_amdgcn_s_barrier();
  }
  float bc[4];
  #pragma unroll
  for (int ci = 0; ci < 4; ++ci) bc[ci] = bcls[bn * 128 + wc * 64 + ci * 16 + l15];
  #pragma unroll
  for (int ci = 0; ci < 4; ++ci) {
    const int col = bn * 128 + wc * 64 + ci * 16 + l15;
    #pragma unroll
    for (int mi = 0; mi < 4; ++mi)
      #pragma unroll
      for (int r = 0; r < 4; ++r) {
        const int row = bm * 128 + wm * 64 + mi * 16 + l4 * 4 + r;
        out[(size_t)row * 32000 + col] = acc[mi][ci][r] + bc[ci];
      }
  }
  __syncthreads();
  CLS_EPILOGUE()
}

// ---------------- softmax: partial merge + subtract ----------------
__global__ void __launch_bounds__(256)
lsm_red(const float* __restrict__ pmax, const float* __restrict__ psum,
        float* __restrict__ logz) {
  __shared__ float rm[256], rs[256];
  const int r = blockIdx.x, b = threadIdx.x;
  float m = -3.0e38f, s = 0.0f;
  if (b < 250) { m = pmax[(size_t)r * 256 + b]; s = psum[(size_t)r * 256 + b]; }
  rm[b] = m; rs[b] = s; __syncthreads();
  for (int st = 128; st > 0; st >>= 1) {
    if (b < st) {
      const float m2 = rm[b + st], s2 = rs[b + st];
      const float M = fmaxf(rm[b], m2);
      rs[b] = rs[b] * __expf(rm[b] - M) + s2 * __expf(m2 - M);
      rm[b] = M;
    }
    __syncthreads();
  }
  if (b == 0) logz[r] = rm[0] + logf(rs[0]);
}

__global__ void __launch_bounds__(256)
sub_k(float* __restrict__ out, const float* __restrict__ logz) {
  const int r = blockIdx.x;
  const float z = logz[r];
  float4* p = (float4*)(out + (size_t)r * 32000);
  for (int v = threadIdx.x; v < 8000; v += 256) {
    float4 x = p[v];
    x.x -= z; x.y -= z; x.z -= z; x.w -= z;
    p[v] = x;
  }
}

// ---------------- host ----------------
extern "C" void kernel_launch(void* const* d_in, const int* in_sizes, int n_in,
                              void* d_out, int out_size, void* d_ws, size_t ws_size,
                              hipStream_t stream) {
  (void)in_sizes; (void)n_in; (void)out_size;
  const int*   tgt  = (const int*)d_in[1];
  const float* h0   = (const float*)d_in[2];
  const float* c0   = (const float*)d_in[3];
  const float* emb  = (const float*)d_in[4];
  const float* Wih  = (const float*)d_in[5];
  const float* Whh  = (const float*)d_in[6];
  const float* bih  = (const float*)d_in[7];
  const float* bhh  = (const float*)d_in[8];
  const float* Wcls = (const float*)d_in[9];
  const float* bcls = (const float*)d_in[10];

  float* out  = (float*)d_out;
  float* outh = out + (size_t)kT * kB * kV;
  float* outc = outh + (size_t)kL * kB * kH;

  const size_t SZ_WPACK = 67108864;
  const size_t SZ_WCLS  = 65536000;
  const size_t SZ_X     = 8388608;
  const size_t SZ_HBALL = 34078720;   // L*65*B*H bf16
  const size_t SZ_BSUM  = 65536;
  const size_t SZ_FLAGS = 16384;
  const size_t SZ_PM    = 4194304;    // 4096*256 f32
  const size_t FULL_REQ = SZ_WPACK + SZ_WCLS + SZ_X + SZ_HBALL + SZ_BSUM + SZ_FLAGS + 2 * SZ_PM + 16384;
  const bool full = (ws_size >= FULL_REQ);

  char* ws = (char*)d_ws;
  size_t off = 0;
  u16* wpack = (u16*)(ws + off); off += SZ_WPACK;
  u16* wclsb = nullptr;
  if (full) { wclsb = (u16*)(ws + off); off += SZ_WCLS; }
  u16*   X     = (u16*)(ws + off); off += SZ_X;
  u16*   hball = (u16*)(ws + off); off += SZ_HBALL;
  float* bsum  = (float*)(ws + off); off += SZ_BSUM;
  Flag*  flags = (Flag*)(ws + off);  off += SZ_FLAGS;
  float* pmax  = (float*)(ws + off); off += SZ_PM;
  float* psum  = (float*)(ws + off); off += SZ_PM;
  float* logz  = (float*)(ws + off); off += 16384;

  pack_lstm<<<16384, 256, 0, stream>>>(Wih, Whh, wpack);
  if (full) pack_cls<<<16000, 256, 0, stream>>>(Wcls, wclsb);
  pack_x   <<<2048,  256, 0, stream>>>(emb, tgt, X);
  pack_init<<<192,   256, 0, stream>>>(h0, bih, bhh, hball, bsum);
  hipMemsetAsync(flags, 0, SZ_FLAGS, stream);

  void* args[] = { (void*)&wpack, (void*)&X, (void*)&hball, (void*)&bsum,
                   (void*)&c0, (void*)&outh, (void*)&outc, (void*)&flags };
  hipLaunchCooperativeKernel((const void*)lstm_coop, dim3(256), dim3(1024), args, 0, stream);

  const u16* h3a = hball + (size_t)3 * 65 * 65536 + 65536;
  if (full) cls_gemm    <<<dim3(250, 32), 256, 0, stream>>>(h3a, wclsb, bcls, out, pmax, psum);
  else      cls_gemm_f32<<<dim3(250, 32), 256, 0, stream>>>(h3a, Wcls,  bcls, out, pmax, psum);
  lsm_red<<<4096, 256, 0, stream>>>(pmax, psum, logz);
  sub_k  <<<4096, 256, 0, stream>>>(out, logz);
}

// Round 8
// 1364.895 us; speedup vs baseline: 4.8615x; 1.0358x over previous
//
#include <hip/hip_runtime.h>

using u16 = unsigned short;
using u32 = unsigned int;

typedef __bf16 bf16x8 __attribute__((ext_vector_type(8)));
typedef float  f32x4  __attribute__((ext_vector_type(4)));
typedef u16    u16x8  __attribute__((ext_vector_type(8)));

static constexpr int kV = 32000, kH = 1024, kB = 64, kT = 64, kL = 4, kEOS = 2;

struct Flag { int v; int pad[15]; };   // one 64B line per flag

__device__ __forceinline__ u16 f2bf(float f) {
  u32 u = __float_as_uint(f);
  u = (u + 0x7fffu + ((u >> 16) & 1u)) >> 16;
  return (u16)u;
}
__device__ __forceinline__ float sigf(float x)   { return 1.0f / (1.0f + __expf(-x)); }
__device__ __forceinline__ float tanhf_(float x) { return 1.0f - 2.0f / (__expf(2.0f * x) + 1.0f); }

typedef const __attribute__((address_space(1))) u32* gas_ptr;
typedef __attribute__((address_space(3))) u32*       las_ptr;
__device__ __forceinline__ void async16(const u16* g, u16* l) {
  __builtin_amdgcn_global_load_lds((gas_ptr)g, (las_ptr)l, 16, 0, 0);
}

__device__ __forceinline__ void spin_ge(const int* p, int tgt) {
  while (__hip_atomic_load(p, __ATOMIC_RELAXED, __HIP_MEMORY_SCOPE_AGENT) < tgt)
    __builtin_amdgcn_s_sleep(2);
}

// Frag-packed 64x1024 bf16 matrix: [mtile=b>>4][ks=k>>5][lane=((k>>3)&3)*16+(b&15)][elem=k&7]
__device__ __forceinline__ size_t packed_off(int b, int k) {
  return (size_t)(((b >> 4) * 32 + (k >> 5)) * 512 + (((k >> 3) & 3) * 16 + (b & 15)) * 8 + (k & 7));
}

// ---------------- prep kernels ----------------

// wpack[lblk(256)][mat(2)][kk(32)][cf(4)][lane(64)][8], lblk = lay*64+cb
__global__ void pack_lstm(const float* __restrict__ Wih, const float* __restrict__ Whh,
                          u16* __restrict__ wpack) {
  const int cid  = blockIdx.x * 256 + threadIdx.x;   // < 4,194,304
  const int lane = cid & 63;
  const int cf   = (cid >> 6) & 3;
  const int kk   = (cid >> 8) & 31;
  const int mt   = (cid >> 13) & 1;
  const int blk  = cid >> 14;
  const int lay = blk >> 6, cb = blk & 63;
  const int wr = cf * 1024 + cb * 16 + (lane & 15);
  const int kb = kk * 32 + (lane >> 4) * 8;
  const float* src = (mt ? Whh : Wih) + ((size_t)lay * 4096 + wr) * 1024 + kb;
  const float4* s4 = (const float4*)src;
  float4 v0 = s4[0], v1 = s4[1];
  u16x8 r;
  r[0]=f2bf(v0.x); r[1]=f2bf(v0.y); r[2]=f2bf(v0.z); r[3]=f2bf(v0.w);
  r[4]=f2bf(v1.x); r[5]=f2bf(v1.y); r[6]=f2bf(v1.z); r[7]=f2bf(v1.w);
  *(u16x8*)(wpack + (size_t)cid * 8) = r;
}

__global__ void pack_cls(const float* __restrict__ W, u16* __restrict__ o) {
  const size_t cid = (size_t)blockIdx.x * 256 + threadIdx.x;  // < 4,096,000
  const float4* s4 = (const float4*)(W + cid * 8);
  float4 v0 = s4[0], v1 = s4[1];
  u16x8 r;
  r[0]=f2bf(v0.x); r[1]=f2bf(v0.y); r[2]=f2bf(v0.z); r[3]=f2bf(v0.w);
  r[4]=f2bf(v1.x); r[5]=f2bf(v1.y); r[6]=f2bf(v1.z); r[7]=f2bf(v1.w);
  *(u16x8*)(o + cid * 8) = r;
}

__global__ void pack_x(const float* __restrict__ emb, const int* __restrict__ tgt,
                       u16* __restrict__ X) {
  const int cid = blockIdx.x * 256 + threadIdx.x;    // < 524,288
  const int kc = cid & 127, b = (cid >> 7) & 63, t = cid >> 13;
  const int tok = (t == 0) ? kEOS : tgt[b * 64 + t - 1];
  const float4* s4 = (const float4*)(emb + (size_t)tok * 1024 + kc * 8);
  float4 v0 = s4[0], v1 = s4[1];
  u16x8 r;
  r[0]=f2bf(v0.x); r[1]=f2bf(v0.y); r[2]=f2bf(v0.z); r[3]=f2bf(v0.w);
  r[4]=f2bf(v1.x); r[5]=f2bf(v1.y); r[6]=f2bf(v1.z); r[7]=f2bf(v1.w);
  *(u16x8*)(X + (size_t)t * 65536 + packed_off(b, kc * 8)) = r;
}

__global__ void pack_init(const float* __restrict__ h0, const float* __restrict__ bih,
                          const float* __restrict__ bhh, u16* __restrict__ hball,
                          float* __restrict__ bsum) {
  const int cid = blockIdx.x * 256 + threadIdx.x;    // grid = 192*256
  if (cid < 32768) {
    const int kc = cid & 127, row = cid >> 7;        // row = lay*64 + b
    const int lay = row >> 6, b = row & 63;
    const float4* s4 = (const float4*)(h0 + (size_t)cid * 8);
    float4 v0 = s4[0], v1 = s4[1];
    u16x8 r;
    r[0]=f2bf(v0.x); r[1]=f2bf(v0.y); r[2]=f2bf(v0.z); r[3]=f2bf(v0.w);
    r[4]=f2bf(v1.x); r[5]=f2bf(v1.y); r[6]=f2bf(v1.z); r[7]=f2bf(v1.w);
    *(u16x8*)(hball + (size_t)lay * 65 * 65536 + packed_off(b, kc * 8)) = r;
  } else {
    const int i = cid - 32768;   // < 16384
    bsum[i] = bih[i] + bhh[i];
  }
}

// ---------------- recurrence: 256 blocks x 1024 thr (16 waves, 4/SIMD) ----------------
// XCD-affinity swizzle: lay = (blk>>1)&3, cb = (blk>>3)*2 + (blk&1).
//   blk%8 = XCD (round-robin heuristic) -> each layer owns XCDs {2l, 2l+1}; all 64
//   same-layer blocks share those L2s, so the per-step 256KB activation reads are
//   L2-hits after the first touch (perf-only assumption; correctness unaffected).
// Wave role: cmat = w>>3, cwc = (w>>1)&3 (16-col frag), ckh = w&1 (k parity).
// breg[16] register-resident. K in 8 chunks; ring-3 LDS, depth-2 prefetch,
// counted vmcnt(2) (never 0 in steady state).
__global__ void __launch_bounds__(1024, 4)
lstm_coop(const u16* __restrict__ wpack, const u16* __restrict__ xall,
          u16* __restrict__ hball, const float* __restrict__ bsum,
          const float* __restrict__ c0, float* __restrict__ outh, float* __restrict__ outc,
          Flag* flags) {
  __shared__ u16 stg[3][32][512];    // 96 KB: [buf][mat*16 + mtile*4 + ksl][lane*8]
  __shared__ float Gc[2][64][66];    // 33.8 KB: partials by cmat (two-phase over ckh)

  const int tid = threadIdx.x, lane = tid & 63, wave = tid >> 6;
  const int l15 = lane & 15, l4 = lane >> 4;
  const int cmat = wave >> 3, cwc = (wave >> 1) & 3, ckh = wave & 1;
  const int blk = blockIdx.x;
  const int lay = (blk >> 1) & 3;
  const int cb  = ((blk >> 3) << 1) | (blk & 1);
  const int u0 = cb << 4;
  const int ub = tid >> 4, uu = tid & 15;       // cell update: 1 batch row, 1 unit

  float creg = c0[((size_t)lay * 64 + ub) * 1024 + u0 + uu];
  float bsv[4];
  #pragma unroll
  for (int g = 0; g < 4; ++g) bsv[g] = bsum[lay * 4096 + g * 1024 + u0 + uu];

  // weights -> registers: breg[j] = k-slice kk = 2*j + ckh, col-frag cwc, matrix cmat
  const size_t wbase = (size_t)(lay * 64 + cb) * 131072;
  bf16x8 breg[16];
  #pragma unroll
  for (int j = 0; j < 16; ++j)
    breg[j] = *(const bf16x8*)(wpack + wbase
        + (size_t)(((cmat * 32 + 2 * j + ckh) * 4) + cwc) * 512 + lane * 8);

  // staging role: this wave stages tiles j = wave*2 + {0,1} of each chunk
  const int j0 = wave * 2, j1 = wave * 2 + 1;
  const int m2a = j0 >> 4, mta = (j0 >> 2) & 3, ksla = j0 & 3;
  const int m2b = j1 >> 4, mtb = (j1 >> 2) & 3, kslb = j1 & 3;

  u16* hlay = hball + (size_t)lay * 65 * 65536;
  const u16* hprev = (lay == 0) ? xall : (hball + (size_t)(lay - 1) * 65 * 65536);

  #pragma unroll 1
  for (int t = 0; t < kT; ++t) {
    // --- dependency waits: 128 spinners on distinct flag lines ---
    if (t > 0 && tid < 64)                 spin_ge(&flags[lay * 64 + tid].v, t);
    if (lay > 0 && tid >= 64 && tid < 128) spin_ge(&flags[(lay - 1) * 64 + (tid - 64)].v, t + 1);
    __syncthreads();

    const u16* xsrc = (lay == 0) ? (xall + (size_t)t * 65536)
                                 : (hprev + (size_t)(t + 1) * 65536);
    const u16* hsrc = hlay + (size_t)t * 65536;   // h(t-1) = slot t

    const u16* ga = (m2a ? hsrc : xsrc) + (size_t)((mta * 32 + ksla) * 512) + lane * 8;
    const u16* gb = (m2b ? hsrc : xsrc) + (size_t)((mtb * 32 + kslb) * 512) + lane * 8;

    auto STAGE = [&](int c) {   // chunk c: k-slices c*4 + {ksla,kslb}
      async16(ga + (size_t)c * 2048, &stg[c % 3][m2a * 16 + mta * 4 + ksla][0]);
      async16(gb + (size_t)c * 2048, &stg[c % 3][m2b * 16 + mtb * 4 + kslb][0]);
    };

    f32x4 acc[4] = {};
    STAGE(0); STAGE(1);
    #pragma unroll
    for (int c = 0; c < 8; ++c) {
      if (c < 7) asm volatile("s_waitcnt vmcnt(2)" ::: "memory");
      else       asm volatile("s_waitcnt vmcnt(0)" ::: "memory");
      __builtin_amdgcn_s_barrier();
      asm volatile("" ::: "memory");
      if (c < 6) STAGE(c + 2);
      const u16* As = &stg[c % 3][cmat * 16][0];
      #pragma unroll
      for (int s = 0; s < 2; ++s) {
        const int ksl = 2 * s + ckh;
        bf16x8 a[4];
        #pragma unroll
        for (int m = 0; m < 4; ++m)
          a[m] = *(const bf16x8*)(As + (m * 4 + ksl) * 512 + lane * 8);
        #pragma unroll
        for (int m = 0; m < 4; ++m)
          acc[m] = __builtin_amdgcn_mfma_f32_16x16x32_bf16(a[m], breg[2 * c + s], acc[m], 0, 0, 0);
      }
    }

    // --- two-phase partial reduction into Gc[cmat] (ckh=0 writes, ckh=1 adds) ---
    if (ckh == 0) {
      #pragma unroll
      for (int m = 0; m < 4; ++m)
        #pragma unroll
        for (int r = 0; r < 4; ++r)
          Gc[cmat][m * 16 + l4 * 4 + r][cwc * 16 + l15] = acc[m][r];
    }
    __syncthreads();
    if (ckh == 1) {
      #pragma unroll
      for (int m = 0; m < 4; ++m)
        #pragma unroll
        for (int r = 0; r < 4; ++r)
          Gc[cmat][m * 16 + l4 * 4 + r][cwc * 16 + l15] += acc[m][r];
    }
    __syncthreads();

    // --- cell update ---
    float sg[4];
    #pragma unroll
    for (int g = 0; g < 4; ++g) {
      const int col = g * 16 + uu;
      sg[g] = Gc[0][ub][col] + Gc[1][ub][col] + bsv[g];
    }
    const float c2 = sigf(sg[1]) * creg + sigf(sg[0]) * tanhf_(sg[2]);
    const float h2 = sigf(sg[3]) * tanhf_(c2);
    creg = c2;
    const u16 hv = f2bf(h2);
    if (t == kT - 1) {
      outh[((size_t)lay * 64 + ub) * 1024 + u0 + uu] = h2;
      outc[((size_t)lay * 64 + ub) * 1024 + u0 + uu] = c2;
    }
    // publish: pair adjacent units into one u32 agent-scope store
    const u32 other = __shfl_xor((u32)hv, 1);
    if ((tid & 1) == 0) {
      const u32 hpair = (u32)hv | (other << 16);
      u32* hdst = (u32*)(hlay + (size_t)(t + 1) * 65536 + packed_off(ub, u0 + uu));
      __hip_atomic_store(hdst, hpair, __ATOMIC_RELAXED, __HIP_MEMORY_SCOPE_AGENT);
    }
    __syncthreads();   // drains vmcnt: h stores coherent before flag
    if (tid == 0)
      __hip_atomic_store(&flags[lay * 64 + cb].v, t + 1, __ATOMIC_RELAXED, __HIP_MEMORY_SCOPE_AGENT);
  }
}

// ---------------- classifier GEMM + fused row-stats epilogue ----------------
#define CLS_EPILOGUE()                                                                     \
  {                                                                                        \
    float* sR = (float*)&sA[0][0];                                                         \
    _Pragma("unroll")                                                                      \
    for (int mi = 0; mi < 4; ++mi) {                                                       \
      _Pragma("unroll")                                                                    \
      for (int r = 0; r < 4; ++r) {                                                        \
        float v[4];                                                                        \
        _Pragma("unroll")                                                                  \
        for (int ci = 0; ci < 4; ++ci) v[ci] = acc[mi][ci][r] + bc[ci];                     \
        float mx = fmaxf(fmaxf(v[0], v[1]), fmaxf(v[2], v[3]));                            \
        mx = fmaxf(mx, __shfl_xor(mx, 1)); mx = fmaxf(mx, __shfl_xor(mx, 2));              \
        mx = fmaxf(mx, __shfl_xor(mx, 4)); mx = fmaxf(mx, __shfl_xor(mx, 8));              \
        float ss = __expf(v[0]-mx) + __expf(v[1]-mx) + __expf(v[2]-mx) + __expf(v[3]-mx);  \
        ss += __shfl_xor(ss, 1); ss += __shfl_xor(ss, 2);                                  \
        ss += __shfl_xor(ss, 4); ss += __shfl_xor(ss, 8);                                  \
        const int lr = wm * 64 + mi * 16 + l4 * 4 + r;                                     \
        if (wc == 0 && l15 == 0) { sR[lr * 2] = mx; sR[lr * 2 + 1] = ss; }                 \
        __syncthreads();                                                                   \
        if (wc == 1 && l15 == 0) {                                                         \
          const float m0 = sR[lr * 2], s0 = sR[lr * 2 + 1];                                \
          const float M = fmaxf(m0, mx);                                                   \
          const float S = s0 * __expf(m0 - M) + ss * __expf(mx - M);                       \
          const int grow = bm * 128 + lr;                                                  \
          pmax[(size_t)grow * 256 + bn] = M;                                               \
          psum[(size_t)grow * 256 + bn] = S;                                               \
        }                                                                                  \
        __syncthreads();                                                                   \
      }                                                                                    \
    }                                                                                      \
  }

__global__ void __launch_bounds__(256)
cls_gemm(const u16* __restrict__ A, const u16* __restrict__ Bw,
         const float* __restrict__ bcls, float* __restrict__ out,
         float* __restrict__ pmax, float* __restrict__ psum) {
  __shared__ u16 sA[2][4096], sB[2][4096];
  const int tid = threadIdx.x, lane = tid & 63, wave = tid >> 6;
  const int wm = wave >> 1, wc = wave & 1;
  const int l15 = lane & 15, l4 = lane >> 4;
  const int bn = blockIdx.x, bm = blockIdx.y;
  const u16* Ab = A  + (size_t)bm * 131072;
  const u16* Bb = Bw + (size_t)bn * 131072;

  auto STAGE = [&](int kk) {
    u16* dA = sA[kk & 1]; u16* dB = sB[kk & 1];
    #pragma unroll
    for (int q = 0; q < 4; ++q) {
      const int u = wave * 4 + q;
      if (u < 8) {
        const u16* g = Ab + (size_t)(u >> 2) * 65536 + (size_t)(((u & 3) * 32 + kk) * 512) + lane * 8;
        async16(g, dA + u * 512);
      } else {
        const int v = u & 7;
        const u16* g = Bb + (size_t)((v & 1) * 64 + lane) * 1024 + kk * 32 + (v >> 1) * 8;
        async16(g, dB + v * 512);
      }
    }
  };

  f32x4 acc[4][4] = {};
  STAGE(0);
  for (int kk = 0; kk < 32; ++kk) {
    if (kk < 31) { STAGE(kk + 1); asm volatile("s_waitcnt vmcnt(4)" ::: "memory"); }
    else         asm volatile("s_waitcnt vmcnt(0)" ::: "memory");
    __builtin_amdgcn_s_barrier();
    asm volatile("" ::: "memory");
    const u16* aS = sA[kk & 1]; const u16* bS = sB[kk & 1];
    bf16x8 av[4], bv[4];
    #pragma unroll
    for (int mi = 0; mi < 4; ++mi) av[mi] = *(const bf16x8*)(aS + (wm * 4 + mi) * 512 + lane * 8);
    #pragma unroll
    for (int ci = 0; ci < 4; ++ci) bv[ci] = *(const bf16x8*)(bS + l4 * 1024 + (wc * 64 + ci * 16 + l15) * 8);
    #pragma unroll
    for (int mi = 0; mi < 4; ++mi)
      #pragma unroll
      for (int ci = 0; ci < 4; ++ci)
        acc[mi][ci] = __builtin_amdgcn_mfma_f32_16x16x32_bf16(av[mi], bv[ci], acc[mi][ci], 0, 0, 0);
    asm volatile("" ::: "memory");
    __builtin_amdgcn_s_barrier();
  }
  float bc[4];
  #pragma unroll
  for (int ci = 0; ci < 4; ++ci) bc[ci] = bcls[bn * 128 + wc * 64 + ci * 16 + l15];
  #pragma unroll
  for (int ci = 0; ci < 4; ++ci) {
    const int col = bn * 128 + wc * 64 + ci * 16 + l15;
    #pragma unroll
    for (int mi = 0; mi < 4; ++mi)
      #pragma unroll
      for (int r = 0; r < 4; ++r) {
        const int row = bm * 128 + wm * 64 + mi * 16 + l4 * 4 + r;
        out[(size_t)row * 32000 + col] = acc[mi][ci][r] + bc[ci];
      }
  }
  __syncthreads();
  CLS_EPILOGUE()
}

__global__ void __launch_bounds__(256)
cls_gemm_f32(const u16* __restrict__ A, const float* __restrict__ Bw,
             const float* __restrict__ bcls, float* __restrict__ out,
             float* __restrict__ pmax, float* __restrict__ psum) {
  __shared__ u16 sA[2][4096], sB[2][4096];
  const int tid = threadIdx.x, lane = tid & 63, wave = tid >> 6;
  const int wm = wave >> 1, wc = wave & 1;
  const int l15 = lane & 15, l4 = lane >> 4;
  const int bn = blockIdx.x, bm = blockIdx.y;
  const u16*  Ab = A  + (size_t)bm * 131072;
  const float* Bb = Bw + (size_t)bn * 131072;

  auto LOADB = [&](int kk, u16x8* rb) {
    #pragma unroll
    for (int q = 0; q < 2; ++q) {
      const int p = tid + q * 256, row = p & 127, khi = p >> 7;
      const float4* s4 = (const float4*)(Bb + (size_t)row * 1024 + kk * 32 + khi * 8);
      float4 v0 = s4[0], v1 = s4[1];
      u16x8 r;
      r[0]=f2bf(v0.x); r[1]=f2bf(v0.y); r[2]=f2bf(v0.z); r[3]=f2bf(v0.w);
      r[4]=f2bf(v1.x); r[5]=f2bf(v1.y); r[6]=f2bf(v1.z); r[7]=f2bf(v1.w);
      rb[q] = r;
    }
  };
  auto WRITEB = [&](int kk, const u16x8* rb) {
    u16* dB = sB[kk & 1];
    #pragma unroll
    for (int q = 0; q < 2; ++q) *(u16x8*)(dB + (tid + q * 256) * 8) = rb[q];
  };
  auto STAGE_A = [&](int kk) {
    u16* dA = sA[kk & 1];
    #pragma unroll
    for (int q = 0; q < 2; ++q) {
      const int v = wave * 2 + q;
      const u16* g = Ab + (size_t)(v >> 2) * 65536 + (size_t)(((v & 3) * 32 + kk) * 512) + lane * 8;
      async16(g, dA + v * 512);
    }
  };

  f32x4 acc[4][4] = {};
  {
    u16x8 rb[2];
    LOADB(0, rb); STAGE_A(0); WRITEB(0, rb);
  }
  for (int kk = 0; kk < 32; ++kk) {
    if (kk < 31) {
      u16x8 rb[2];
      LOADB(kk + 1, rb);
      STAGE_A(kk + 1);
      WRITEB(kk + 1, rb);
    } else {
      asm volatile("s_waitcnt vmcnt(0)" ::: "memory");
    }
    __builtin_amdgcn_s_barrier();
    asm volatile("" ::: "memory");
    const u16* aS = sA[kk & 1]; const u16* bS = sB[kk & 1];
    bf16x8 av[4], bv[4];
    #pragma unroll
    for (int mi = 0; mi < 4; ++mi) av[mi] = *(const bf16x8*)(aS + (wm * 4 + mi) * 512 + lane * 8);
    #pragma unroll
    for (int ci = 0; ci < 4; ++ci) bv[ci] = *(const bf16x8*)(bS + l4 * 1024 + (wc * 64 + ci * 16 + l15) * 8);
    #pragma unroll
    for (int mi = 0; mi < 4; ++mi)
      #pragma unroll
      for (int ci = 0; ci < 4; ++ci)
        acc[mi][ci] = __builtin_amdgcn_mfma_f32_16x16x32_bf16(av[mi], bv[ci], acc[mi][ci], 0, 0, 0);
    asm volatile("" ::: "memory");
    __builtin_amdgcn_s_barrier();
  }
  float bc[4];
  #pragma unroll
  for (int ci = 0; ci < 4; ++ci) bc[ci] = bcls[bn * 128 + wc * 64 + ci * 16 + l15];
  #pragma unroll
  for (int ci = 0; ci < 4; ++ci) {
    const int col = bn * 128 + wc * 64 + ci * 16 + l15;
    #pragma unroll
    for (int mi = 0; mi < 4; ++mi)
      #pragma unroll
      for (int r = 0; r < 4; ++r) {
        const int row = bm * 128 + wm * 64 + mi * 16 + l4 * 4 + r;
        out[(size_t)row * 32000 + col] = acc[mi][ci][r] + bc[ci];
      }
  }
  __syncthreads();
  CLS_EPILOGUE()
}

// ---------------- softmax: partial merge + subtract ----------------
__global__ void __launch_bounds__(256)
lsm_red(const float* __restrict__ pmax, const float* __restrict__ psum,
        float* __restrict__ logz) {
  __shared__ float rm[256], rs[256];
  const int r = blockIdx.x, b = threadIdx.x;
  float m = -3.0e38f, s = 0.0f;
  if (b < 250) { m = pmax[(size_t)r * 256 + b]; s = psum[(size_t)r * 256 + b]; }
  rm[b] = m; rs[b] = s; __syncthreads();
  for (int st = 128; st > 0; st >>= 1) {
    if (b < st) {
      const float m2 = rm[b + st], s2 = rs[b + st];
      const float M = fmaxf(rm[b], m2);
      rs[b] = rs[b] * __expf(rm[b] - M) + s2 * __expf(m2 - M);
      rm[b] = M;
    }
    __syncthreads();
  }
  if (b == 0) logz[r] = rm[0] + logf(rs[0]);
}

__global__ void __launch_bounds__(256)
sub_k(float* __restrict__ out, const float* __restrict__ logz) {
  const int r = blockIdx.x;
  const float z = logz[r];
  float4* p = (float4*)(out + (size_t)r * 32000);
  for (int v = threadIdx.x; v < 8000; v += 256) {
    float4 x = p[v];
    x.x -= z; x.y -= z; x.z -= z; x.w -= z;
    p[v] = x;
  }
}

// ---------------- host ----------------
extern "C" void kernel_launch(void* const* d_in, const int* in_sizes, int n_in,
                              void* d_out, int out_size, void* d_ws, size_t ws_size,
                              hipStream_t stream) {
  (void)in_sizes; (void)n_in; (void)out_size;
  const int*   tgt  = (const int*)d_in[1];
  const float* h0   = (const float*)d_in[2];
  const float* c0   = (const float*)d_in[3];
  const float* emb  = (const float*)d_in[4];
  const float* Wih  = (const float*)d_in[5];
  const float* Whh  = (const float*)d_in[6];
  const float* bih  = (const float*)d_in[7];
  const float* bhh  = (const float*)d_in[8];
  const float* Wcls = (const float*)d_in[9];
  const float* bcls = (const float*)d_in[10];

  float* out  = (float*)d_out;
  float* outh = out + (size_t)kT * kB * kV;
  float* outc = outh + (size_t)kL * kB * kH;

  const size_t SZ_WPACK = 67108864;
  const size_t SZ_WCLS  = 65536000;
  const size_t SZ_X     = 8388608;
  const size_t SZ_HBALL = 34078720;   // L*65*B*H bf16
  const size_t SZ_BSUM  = 65536;
  const size_t SZ_FLAGS = 16384;
  const size_t SZ_PM    = 4194304;    // 4096*256 f32
  const size_t FULL_REQ = SZ_WPACK + SZ_WCLS + SZ_X + SZ_HBALL + SZ_BSUM + SZ_FLAGS + 2 * SZ_PM + 16384;
  const bool full = (ws_size >= FULL_REQ);

  char* ws = (char*)d_ws;
  size_t off = 0;
  u16* wpack = (u16*)(ws + off); off += SZ_WPACK;
  u16* wclsb = nullptr;
  if (full) { wclsb = (u16*)(ws + off); off += SZ_WCLS; }
  u16*   X     = (u16*)(ws + off); off += SZ_X;
  u16*   hball = (u16*)(ws + off); off += SZ_HBALL;
  float* bsum  = (float*)(ws + off); off += SZ_BSUM;
  Flag*  flags = (Flag*)(ws + off);  off += SZ_FLAGS;
  float* pmax  = (float*)(ws + off); off += SZ_PM;
  float* psum  = (float*)(ws + off); off += SZ_PM;
  float* logz  = (float*)(ws + off); off += 16384;

  pack_lstm<<<16384, 256, 0, stream>>>(Wih, Whh, wpack);
  if (full) pack_cls<<<16000, 256, 0, stream>>>(Wcls, wclsb);
  pack_x   <<<2048,  256, 0, stream>>>(emb, tgt, X);
  pack_init<<<192,   256, 0, stream>>>(h0, bih, bhh, hball, bsum);
  hipMemsetAsync(flags, 0, SZ_FLAGS, stream);

  void* args[] = { (void*)&wpack, (void*)&X, (void*)&hball, (void*)&bsum,
                   (void*)&c0, (void*)&outh, (void*)&outc, (void*)&flags };
  hipLaunchCooperativeKernel((const void*)lstm_coop, dim3(256), dim3(1024), args, 0, stream);

  const u16* h3a = hball + (size_t)3 * 65 * 65536 + 65536;
  if (full) cls_gemm    <<<dim3(250, 32), 256, 0, stream>>>(h3a, wclsb, bcls, out, pmax, psum);
  else      cls_gemm_f32<<<dim3(250, 32), 256, 0, stream>>>(h3a, Wcls,  bcls, out, pmax, psum);
  lsm_red<<<4096, 256, 0, stream>>>(pmax, psum, logz);
  sub_k  <<<4096, 256, 0, stream>>>(out, logz);
}